// Round 2
// baseline (392.251 us; speedup 1.0000x reference)
//
#include <hip/hip_runtime.h>
#include <hip/hip_fp16.h>

#define D 128
#define HB 128        // histogram blocks per role (edge-partitioned)
#define HT 1024       // threads per histogram block
#define WMAX 12800    // LDS histogram words (4 nodes/word, byte counters)

struct alignas(16) H8 { __half2 h[4]; };
typedef _Float16 v8h __attribute__((ext_vector_type(8)));
typedef float v4f __attribute__((ext_vector_type(4)));
typedef int v4i __attribute__((ext_vector_type(4)));

// ---------------------------------------------------------------------------
// Edge-partitioned LDS histogram (R8-proven) + merged W-prep role (3 tail
// blocks transpose W1/2/3 to fp16 [n][k] for MFMA B-frags).
// Block b histograms its own 6250-edge slice into byte-packed LDS counters;
// dst role captures local rank from ds_add_rtn.
// ---------------------------------------------------------------------------
__global__ __launch_bounds__(HT) void hist_kernel(const int* __restrict__ src,
                                                  const int* __restrict__ dst,
                                                  unsigned* __restrict__ partial_out,
                                                  unsigned* __restrict__ partial_in,
                                                  unsigned char* __restrict__ lrank,
                                                  const float* __restrict__ W1,
                                                  const float* __restrict__ W2,
                                                  const float* __restrict__ W3,
                                                  _Float16* __restrict__ wt,
                                                  int nE, int W, int epb) {
    const int t = threadIdx.x;
    if ((int)blockIdx.x >= 2 * HB) {                 // W-prep role
        const int l = blockIdx.x - 2 * HB;
        const float* Wsrc = (l == 0) ? W1 : ((l == 1) ? W2 : W3);
        _Float16* o = wt + (size_t)l * D * D;
        for (int i = t; i < D * D; i += HT) {
            const int k = i >> 7, n = i & 127;
            o[n * D + k] = (_Float16)Wsrc[i];
        }
        return;
    }
    __shared__ unsigned lcnt[WMAX];
    const bool is_dst = (blockIdx.x < HB);
    const int b = is_dst ? blockIdx.x : (blockIdx.x - HB);
    for (int i = t; i < W; i += HT) lcnt[i] = 0;
    __syncthreads();
    const int e0 = b * epb;
    const int e1 = min(nE, e0 + epb);
    if (is_dst) {
        for (int e = e0 + t; e < e1; e += HT) {
            const int d = dst[e];
            const unsigned sh = (unsigned)(d & 3) * 8u;
            const unsigned old = atomicAdd(&lcnt[d >> 2], 1u << sh);
            lrank[e] = (unsigned char)((old >> sh) & 0xffu);
        }
    } else {
        for (int e = e0 + t; e < e1; e += HT) {
            const int s = src[e];
            atomicAdd(&lcnt[s >> 2], 1u << ((unsigned)(s & 3) * 8u));
        }
    }
    __syncthreads();
    unsigned* g = (is_dst ? partial_in : partial_out) + (size_t)b * W;
    for (int i = t; i < W; i += HT) g[i] = lcnt[i];
}

// ---------------------------------------------------------------------------
// Reduce 128 partials per node-word (byte-parallel; totals < 256).
// ---------------------------------------------------------------------------
__global__ __launch_bounds__(256) void reduce_hist_kernel(const unsigned* __restrict__ partial_out,
                                                          const unsigned* __restrict__ partial_in,
                                                          unsigned* __restrict__ offs_in,
                                                          int* __restrict__ cnt_out,
                                                          int* __restrict__ cnt_in,
                                                          int W, int n, int nbW) {
    const bool is_dst = ((int)blockIdx.x < nbW);
    const int w = (is_dst ? blockIdx.x : (blockIdx.x - nbW)) * 256 + threadIdx.x;
    if (w >= W) return;
    unsigned run = 0;
    if (is_dst) {
#pragma unroll 16
        for (int b = 0; b < HB; ++b) {
            const unsigned c = partial_in[(size_t)b * W + w];
            offs_in[(size_t)b * W + w] = run;
            run += c;
        }
    } else {
#pragma unroll 16
        for (int b = 0; b < HB; ++b) run += partial_out[(size_t)b * W + w];
    }
    int* cnt = is_dst ? cnt_in : cnt_out;
    const int n0 = w * 4;
    const int4 c4 = make_int4((int)(run & 0xffu), (int)((run >> 8) & 0xffu),
                              (int)((run >> 16) & 0xffu), (int)((run >> 24) & 0xffu));
    if (n0 + 3 < n) {
        *(int4*)&cnt[n0] = c4;
    } else {
        const int* cp = &c4.x;
        for (int i = 0; i < 4 && n0 + i < n; ++i) cnt[n0 + i] = cp[i];
    }
}

// ---------------------------------------------------------------------------
// Exclusive scan stage 1.
// ---------------------------------------------------------------------------
__global__ __launch_bounds__(1024) void scan_block_kernel(const int* __restrict__ deg,
                                                          int* __restrict__ rp,
                                                          int* __restrict__ bsum, int n) {
    __shared__ int wsum[16];
    const int t = threadIdx.x;
    const int lane = t & 63;
    const int wid = t >> 6;
    const int i = blockIdx.x * 1024 + t;
    const int v = (i < n) ? deg[i] : 0;
    int s = v;
#pragma unroll
    for (int off = 1; off < 64; off <<= 1) {
        int u = __shfl_up(s, off, 64);
        if (lane >= off) s += u;
    }
    if (lane == 63) wsum[wid] = s;
    __syncthreads();
    if (wid == 0) {
        int ws = (lane < 16) ? wsum[lane] : 0;
#pragma unroll
        for (int off = 1; off < 16; off <<= 1) {
            int u = __shfl_up(ws, off, 64);
            if (lane >= off) ws += u;
        }
        if (lane < 16) wsum[lane] = ws;
    }
    __syncthreads();
    const int excl = s - v + ((wid > 0) ? wsum[wid - 1] : 0);
    if (i < n) rp[i] = excl;
    if (t == 0) bsum[blockIdx.x] = wsum[15];
}

// ---------------------------------------------------------------------------
// Stage 2 fused with norms; rp[n]=E known a priori.
// ---------------------------------------------------------------------------
__global__ __launch_bounds__(1024) void finalize_kernel(int* __restrict__ rp,
                                                        const int* __restrict__ bsum,
                                                        const int* __restrict__ cnt_out,
                                                        const int* __restrict__ cnt_in,
                                                        float* __restrict__ onorm,
                                                        float* __restrict__ inorm,
                                                        int n, int nb, int nE) {
    __shared__ int prefix_s;
    const int t = threadIdx.x;
    if (t < 64) {
        int v = (t < nb && t < (int)blockIdx.x) ? bsum[t] : 0;
#pragma unroll
        for (int off = 1; off < 64; off <<= 1) v += __shfl_xor(v, off, 64);
        if (t == 0) prefix_s = v;
    }
    __syncthreads();
    const int i = blockIdx.x * 1024 + t;
    if (i < n) {
        rp[i] += prefix_s;
        onorm[i] = rsqrtf(fmaxf((float)cnt_out[i], 1.0f));
        inorm[i] = rsqrtf(fmaxf((float)cnt_in[i], 1.0f));
    }
    if (blockIdx.x == 0 && t == 0) rp[n] = nE;
}

// ---------------------------------------------------------------------------
// FUSED: GEMM1 (y1 = (x@W1)*onorm -> fp16, MFMA) + atomic-free CSR fill.
// R12-proven: independent work, disjoint resources; fill blocks carry NO LDS
// so they keep full wave residency.
// ---------------------------------------------------------------------------
__global__ __launch_bounds__(1024) void gemm1_fill_kernel(
    const float* __restrict__ x, const _Float16* __restrict__ wt,
    const float* __restrict__ onorm, __half* __restrict__ y1, int nrows,
    const int* __restrict__ src, const int* __restrict__ dst,
    const unsigned char* __restrict__ lrank, const unsigned* __restrict__ offs_in,
    const int* __restrict__ rp, int* __restrict__ srcs_sorted,
    int nE, int epb, int W, int nGemmBlocks) {
    __shared__ _Float16 sA[128 * 136];
    __shared__ _Float16 sB[128 * 136];
    const int t = threadIdx.x;

    if ((int)blockIdx.x >= nGemmBlocks) {
        // ---- fill role: one edge per thread ----
        const int e = (blockIdx.x - nGemmBlocks) * 1024 + t;
        if (e < nE) {
            const int d = dst[e];
            const int b = e / epb;
            const unsigned off =
                (offs_in[(size_t)b * W + (d >> 2)] >> ((unsigned)(d & 3) * 8u)) & 0xffu;
            srcs_sorted[rp[d] + (int)off + (int)lrank[e]] = src[e];
        }
        return;
    }

    // ---- GEMM role: 128x128 tile, 16 waves ----
    const int row0 = blockIdx.x * 128;
    const int rr = t >> 4;      // 64 staging rows per pass
    const int c8 = t & 15;
#pragma unroll
    for (int pass = 0; pass < 2; ++pass) {
        const int row = pass * 64 + rr;
        *(float4*)&sB[row * 136 + c8 * 8] = *(const float4*)&wt[(size_t)row * D + c8 * 8];
        const int grow = row0 + row;
        float4 u0 = make_float4(0.f, 0.f, 0.f, 0.f);
        float4 u1 = u0;
        if (grow < nrows) {
            const float* ap = x + (size_t)grow * D + c8 * 8;
            u0 = ((const float4*)ap)[0];
            u1 = ((const float4*)ap)[1];
        }
        v8h hv;
        hv[0] = (_Float16)u0.x; hv[1] = (_Float16)u0.y;
        hv[2] = (_Float16)u0.z; hv[3] = (_Float16)u0.w;
        hv[4] = (_Float16)u1.x; hv[5] = (_Float16)u1.y;
        hv[6] = (_Float16)u1.z; hv[7] = (_Float16)u1.w;
        *(v8h*)&sA[row * 136 + c8 * 8] = hv;
    }
    __syncthreads();

    const int w = t >> 6;       // 16 waves
    const int lane = t & 63;
    const int m16 = lane & 15;
    const int quad = lane >> 4;
    const int rt = w >> 1;      // row-tile 0..7
    const int ch = w & 1;       // col half 0..1

    v4f c[4];
#pragma unroll
    for (int ct = 0; ct < 4; ++ct) c[ct] = (v4f){0.f, 0.f, 0.f, 0.f};

#pragma unroll
    for (int ks = 0; ks < 4; ++ks) {
        const v8h a = *(const v8h*)&sA[(rt * 16 + m16) * 136 + ks * 32 + quad * 8];
#pragma unroll
        for (int ct = 0; ct < 4; ++ct) {
            const v8h b = *(const v8h*)&sB[((ch * 4 + ct) * 16 + m16) * 136 + ks * 32 + quad * 8];
            c[ct] = __builtin_amdgcn_mfma_f32_16x16x32_f16(a, b, c[ct], 0, 0, 0);
        }
    }

#pragma unroll
    for (int r = 0; r < 4; ++r) {
        const int row = row0 + rt * 16 + quad * 4 + r;
        if (row < nrows) {
            const float osc = onorm[row];
#pragma unroll
            for (int ct = 0; ct < 4; ++ct) {
                const int col = (ch * 4 + ct) * 16 + m16;
                y1[(size_t)row * D + col] = __float2half(c[ct][r] * osc);
            }
        }
    }
}

// ---------------------------------------------------------------------------
// Aggregation v2: COLUMN-SLICED gather for per-XCD L2 residency.
// Theory: the old wave-per-node 256B gather was fabric-bound (~4.4 TB/s,
// R5/R7/R10/R13 all hit the same floor) because the 12.8 MB fp16 feature
// table cannot fit a 4 MiB per-XCD L2 -> random rows miss ~70% to L3.
// Fix: slice the feature dim into 4 slices of 32 cols (3.2 MB table each)
// and pin slice s to XCDs {s, s+4} via the blockIdx%8 round-robin dispatch.
// Each XCD then gathers ONLY from its own 3.2 MB slice -> L2-resident.
// Streaming traffic (srcs index reads, output stores) is non-temporal so it
// doesn't evict the resident table. Total gather volume unchanged (4x64B vs
// 1x256B per edge); the service point moves L3 -> L2.
// Wave layout: 16 edge slots (rg) x 4 chunks of 16B (c4) = 64B slice row.
// EPI (layer 1): relu(r*inorm+b)*onorm — purely per-column, slices cleanly.
// ---------------------------------------------------------------------------
template <bool EPI>
__global__ __launch_bounds__(256) void aggregate_kernel(const __half* __restrict__ xh,
                                                        const float* __restrict__ onorm,
                                                        const float* __restrict__ inorm,
                                                        const float* __restrict__ bias,
                                                        const int* __restrict__ rp,
                                                        const int* __restrict__ srcs,
                                                        __half* __restrict__ agg,
                                                        int n_nodes, int ngroups) {
    const unsigned b = blockIdx.x;
    const int xcd = (int)(b & 7u);            // blockIdx%8 -> XCD (round-robin)
    const int slice = xcd & 3;                // 32-col slice; XCDs s and s+4 share slice s
    const int node = ((xcd >> 2) * ngroups + (int)(b >> 3)) * 4 + ((int)threadIdx.x >> 6);
    const int lane = threadIdx.x & 63;
    const int rg = lane >> 2;                 // edge slot 0..15
    const int c4 = lane & 3;                  // 16B chunk within the 64B slice row
    if (node >= n_nodes) return;
    const int e0 = rp[node];
    const int e1 = rp[node + 1];
    const __half* xbase = xh + (slice << 5);  // column offset of this slice

    float acc0[8], acc1[8];
#pragma unroll
    for (int j = 0; j < 8; ++j) { acc0[j] = 0.f; acc1[j] = 0.f; }

    auto accum = [&](float* acc, const H8 v) {
#pragma unroll
        for (int j = 0; j < 4; ++j) {
            acc[2 * j]     += __low2float(v.h[j]);
            acc[2 * j + 1] += __high2float(v.h[j]);
        }
    };

    int e = e0;
    for (; e + 32 <= e1; e += 32) {
        const int s0 = __builtin_nontemporal_load(srcs + e + rg);
        const int s1 = __builtin_nontemporal_load(srcs + e + 16 + rg);
        const H8 v0 = ((const H8*)(xbase + (size_t)s0 * D))[c4];
        const H8 v1 = ((const H8*)(xbase + (size_t)s1 * D))[c4];
        accum(acc0, v0);
        accum(acc1, v1);
    }
    if (e + 16 <= e1) {
        const int s0 = __builtin_nontemporal_load(srcs + e + rg);
        accum(acc0, ((const H8*)(xbase + (size_t)s0 * D))[c4]);
        e += 16;
    }
    if (e < e1 && rg < (e1 - e)) {
        const int s0 = __builtin_nontemporal_load(srcs + e + rg);
        accum(acc1, ((const H8*)(xbase + (size_t)s0 * D))[c4]);
    }

    float r[8];
#pragma unroll
    for (int j = 0; j < 8; ++j) r[j] = acc0[j] + acc1[j];
#pragma unroll
    for (int off = 4; off < 64; off <<= 1)
#pragma unroll
        for (int j = 0; j < 8; ++j) r[j] += __shfl_xor(r[j], off, 64);

    if (rg == 0) {
        if (EPI) {
            const float inm = inorm[node];
            const float onm = onorm[node];
            const float4 bv0 = ((const float4*)bias)[slice * 8 + c4 * 2];
            const float4 bv1 = ((const float4*)bias)[slice * 8 + c4 * 2 + 1];
            const float* bp0 = &bv0.x;
            const float* bp1 = &bv1.x;
#pragma unroll
            for (int j = 0; j < 4; ++j) {
                r[j]     = fmaxf(fmaf(r[j],     inm, bp0[j]), 0.f) * onm;
                r[j + 4] = fmaxf(fmaf(r[j + 4], inm, bp1[j]), 0.f) * onm;
            }
        }
        H8 h;
#pragma unroll
        for (int j = 0; j < 4; ++j) h.h[j] = __floats2half2_rn(r[2 * j], r[2 * j + 1]);
        v4i* op = (v4i*)(agg + (size_t)node * D + (slice << 5)) + c4;
        __builtin_nontemporal_store(*(const v4i*)&h, op);
    }
}

// ---------------------------------------------------------------------------
// MFMA GEMM for layers 2/3 (R9-proven). 128x128 tile, fp16 operands, fp32
// acc. LDS stride 136 halves. Epilogue: FULL(*inorm+bias), RELU, OSCALE,
// OUT16. A is fp16 row-major.
// ---------------------------------------------------------------------------
template <bool FULL, bool RELU, bool OSCALE, bool OUT16>
__global__ __launch_bounds__(256) void gemm_mfma_kernel(const __half* __restrict__ Ah,
                                                        const _Float16* __restrict__ Wt,
                                                        const float* __restrict__ bias,
                                                        const float* __restrict__ inorm,
                                                        const float* __restrict__ onorm,
                                                        void* __restrict__ outv, int nrows) {
    __shared__ _Float16 sA[128 * 136];
    __shared__ _Float16 sB[128 * 136];
    const int t = threadIdx.x;
    const int row0 = blockIdx.x * 128;
    const int rr = t >> 4;
    const int c8 = t & 15;

#pragma unroll
    for (int pass = 0; pass < 8; ++pass) {
        const int row = pass * 16 + rr;
        *(float4*)&sB[row * 136 + c8 * 8] = *(const float4*)&Wt[(size_t)row * D + c8 * 8];
        const int grow = row0 + row;
        float4 v = make_float4(0.f, 0.f, 0.f, 0.f);
        if (grow < nrows)
            v = *(const float4*)((const _Float16*)Ah + (size_t)grow * D + c8 * 8);
        *(float4*)&sA[row * 136 + c8 * 8] = v;
    }
    __syncthreads();

    const int w = t >> 6;
    const int lane = t & 63;
    const int m16 = lane & 15;
    const int quad = lane >> 4;

    v4f c[2][8];
#pragma unroll
    for (int rt = 0; rt < 2; ++rt)
#pragma unroll
        for (int ct = 0; ct < 8; ++ct) c[rt][ct] = (v4f){0.f, 0.f, 0.f, 0.f};

#pragma unroll
    for (int ks = 0; ks < 4; ++ks) {
        v8h afr[2], bfr[8];
#pragma unroll
        for (int rt = 0; rt < 2; ++rt)
            afr[rt] = *(const v8h*)&sA[(w * 32 + rt * 16 + m16) * 136 + ks * 32 + quad * 8];
#pragma unroll
        for (int ct = 0; ct < 8; ++ct)
            bfr[ct] = *(const v8h*)&sB[(ct * 16 + m16) * 136 + ks * 32 + quad * 8];
#pragma unroll
        for (int rt = 0; rt < 2; ++rt)
#pragma unroll
            for (int ct = 0; ct < 8; ++ct)
                c[rt][ct] = __builtin_amdgcn_mfma_f32_16x16x32_f16(afr[rt], bfr[ct], c[rt][ct], 0, 0, 0);
    }

#pragma unroll
    for (int rt = 0; rt < 2; ++rt) {
#pragma unroll
        for (int r = 0; r < 4; ++r) {
            const int row = row0 + w * 32 + rt * 16 + quad * 4 + r;
            if (row < nrows) {
                const float inm = FULL ? inorm[row] : 1.0f;
                const float osc = OSCALE ? onorm[row] : 1.0f;
#pragma unroll
                for (int ct = 0; ct < 8; ++ct) {
                    const int col = ct * 16 + m16;
                    float v = c[rt][ct][r];
                    if (FULL) v = fmaf(v, inm, bias[col]);
                    if (RELU) v = fmaxf(v, 0.f);
                    if (OSCALE) v *= osc;
                    if (OUT16) ((__half*)outv)[(size_t)row * D + col] = __float2half(v);
                    else       ((float*)outv)[(size_t)row * D + col] = v;
                }
            }
        }
    }
}

// ---------------------------------------------------------------------------
// Host launch
// ---------------------------------------------------------------------------
extern "C" void kernel_launch(void* const* d_in, const int* in_sizes, int n_in,
                              void* d_out, int out_size, void* d_ws, size_t ws_size,
                              hipStream_t stream) {
    const float* x   = (const float*)d_in[0];
    const int*   src = (const int*)d_in[1];
    const int*   dst = (const int*)d_in[2];
    const float* W1  = (const float*)d_in[3];
    const float* b1  = (const float*)d_in[4];
    const float* W2  = (const float*)d_in[5];
    const float* b2  = (const float*)d_in[6];
    const float* W3  = (const float*)d_in[7];
    const float* b3  = (const float*)d_in[8];

    const int N = in_sizes[0] / D;   // 50000
    const int E = in_sizes[1];       // 800000

    char* p = (char*)d_ws;
    auto alloc = [&](size_t bytes) -> void* {
        void* r = (void*)p;
        p += (bytes + 255) & ~(size_t)255;
        return r;
    };
    int*           cnt_out = (int*)alloc((size_t)N * 4);
    int*           cnt_in  = (int*)alloc((size_t)N * 4);
    int*           rp      = (int*)alloc((size_t)(N + 1) * 4);
    int*           bsum    = (int*)alloc(1024 * 4);
    float*         onorm   = (float*)alloc((size_t)N * 4);
    float*         inorm   = (float*)alloc((size_t)N * 4);
    int*           srcs    = (int*)alloc((size_t)E * 4);
    unsigned char* lrank   = (unsigned char*)alloc((size_t)E);
    _Float16*      wt      = (_Float16*)alloc((size_t)3 * D * D * 2);
    __half*        hbuf0   = (__half*)alloc((size_t)N * D * 2);  // y1, then h2
    __half*        hbuf1   = (__half*)alloc((size_t)N * D * 2);  // h1
    char*          scratch = (char*)alloc((size_t)3 * HB * ((N + 3) / 4) * 4);  // 19.2MB

    const int W = (N + 3) / 4;              // 12500 packed histogram words
    const int epb = (E + HB - 1) / HB;      // 6250 edges per histogram block
    unsigned* partial_in  = (unsigned*)scratch;
    unsigned* partial_out = partial_in + (size_t)HB * W;
    unsigned* offs_in     = partial_out + (size_t)HB * W;
    __half*   abuf        = (__half*)scratch;                  // a2, a3 (fp16)
    float*    outf        = (float*)d_out;

    const int nb = (N + 1023) / 1024;       // 49
    const int nbW = (W + 255) / 256;        // 49
    const int gemmGrid = (N + 127) / 128;   // 391
    const int fillGrid = (E + 1023) / 1024; // 782
    // sliced aggregate: 4 slices x (4 nodes / block); grid = 8 * ngroups so
    // blockIdx%8 pins (slice, node-half) to an XCD. ngroups covers half the
    // node-groups per XCD pair.
    const int aggGroups = (((N + 3) / 4) + 1) / 2;  // 6250
    const int aggGrid = 8 * aggGroups;              // 50000 blocks

    // Graph build (hist + W-prep merged); no global atomics, no memset
    hist_kernel<<<2 * HB + 3, HT, 0, stream>>>(src, dst, partial_out, partial_in, lrank,
                                               W1, W2, W3, wt, E, W, epb);
    reduce_hist_kernel<<<2 * nbW, 256, 0, stream>>>(partial_out, partial_in, offs_in,
                                                    cnt_out, cnt_in, W, N, nbW);
    scan_block_kernel<<<nb, 1024, 0, stream>>>(cnt_in, rp, bsum, N);
    finalize_kernel<<<nb, 1024, 0, stream>>>(rp, bsum, cnt_out, cnt_in, onorm, inorm, N, nb, E);

    // Fused: GEMM1 (y1 = (x@W1)*onorm -> fp16) + CSR fill (independent work)
    gemm1_fill_kernel<<<gemmGrid + fillGrid, 1024, 0, stream>>>(
        x, wt, onorm, hbuf0, N,
        src, dst, lrank, offs_in, rp, srcs, E, epb, W, gemmGrid);

    // Layer 1 aggregate + full epilogue -> h1 fp16
    aggregate_kernel<true><<<aggGrid, 256, 0, stream>>>(
        hbuf0, onorm, inorm, b1, rp, srcs, hbuf1, N, aggGroups);
    // Layer 2: a2 = agg(h1) fp16; h2 = relu((a2@W2)*inorm+b2)*onorm -> fp16
    aggregate_kernel<false><<<aggGrid, 256, 0, stream>>>(
        hbuf1, onorm, inorm, b2, rp, srcs, abuf, N, aggGroups);
    gemm_mfma_kernel<true, true, true, true><<<gemmGrid, 256, 0, stream>>>(
        abuf, wt + (size_t)D * D, b2, inorm, onorm, hbuf0, N);
    // Layer 3: a3 = agg(h2) fp16; out = (a3@W3)*inorm+b3 -> fp32 d_out
    aggregate_kernel<false><<<aggGrid, 256, 0, stream>>>(
        hbuf0, onorm, inorm, b3, rp, srcs, abuf, N, aggGroups);
    gemm_mfma_kernel<true, false, false, false><<<gemmGrid, 256, 0, stream>>>(
        abuf, wt + (size_t)2 * D * D, b3, inorm, onorm, outf, N);
}

// Round 3
// 287.623 us; speedup vs baseline: 1.3638x; 1.3638x over previous
//
#include <hip/hip_runtime.h>
#include <hip/hip_fp16.h>

#define D 128
#define HB 128        // histogram blocks per role (edge-partitioned)
#define HT 1024       // threads per histogram block
#define WMAX 12800    // LDS histogram words (4 nodes/word, byte counters)

struct alignas(16) H8 { __half2 h[4]; };
typedef _Float16 v8h __attribute__((ext_vector_type(8)));
typedef float v4f __attribute__((ext_vector_type(4)));
typedef int v4i __attribute__((ext_vector_type(4)));

// ---------------------------------------------------------------------------
// SLICED feature layout (R14): all fp16 intermediate tables are stored as
// [slice 0..3][node 0..N)[32 cols] (64B rows, each slice a contiguous 3.2MB
// region < 4MiB per-XCD L2). R13's sliced gather proved slice residency cuts
// fabric traffic 2.3x (FETCH 205->89MB) but lost on (a) 2x line overfetch
// (64B rows straddling 128B lines shared between slices), (b) 4x wave count,
// (c) MLP 4->1. This layout + the 4-node-per-wave aggregate fixes all three.
//   addr(node, col) = (col>>5)*N*32 + node*32 + (col&31)   [in halves]
// ---------------------------------------------------------------------------

// ---------------------------------------------------------------------------
// Edge-partitioned LDS histogram (R8-proven) + merged W-prep role (3 tail
// blocks transpose W1/2/3 to fp16 [n][k] for MFMA B-frags).
// ---------------------------------------------------------------------------
__global__ __launch_bounds__(HT) void hist_kernel(const int* __restrict__ src,
                                                  const int* __restrict__ dst,
                                                  unsigned* __restrict__ partial_out,
                                                  unsigned* __restrict__ partial_in,
                                                  unsigned char* __restrict__ lrank,
                                                  const float* __restrict__ W1,
                                                  const float* __restrict__ W2,
                                                  const float* __restrict__ W3,
                                                  _Float16* __restrict__ wt,
                                                  int nE, int W, int epb) {
    const int t = threadIdx.x;
    if ((int)blockIdx.x >= 2 * HB) {                 // W-prep role
        const int l = blockIdx.x - 2 * HB;
        const float* Wsrc = (l == 0) ? W1 : ((l == 1) ? W2 : W3);
        _Float16* o = wt + (size_t)l * D * D;
        for (int i = t; i < D * D; i += HT) {
            const int k = i >> 7, n = i & 127;
            o[n * D + k] = (_Float16)Wsrc[i];
        }
        return;
    }
    __shared__ unsigned lcnt[WMAX];
    const bool is_dst = (blockIdx.x < HB);
    const int b = is_dst ? blockIdx.x : (blockIdx.x - HB);
    for (int i = t; i < W; i += HT) lcnt[i] = 0;
    __syncthreads();
    const int e0 = b * epb;
    const int e1 = min(nE, e0 + epb);
    if (is_dst) {
        for (int e = e0 + t; e < e1; e += HT) {
            const int d = dst[e];
            const unsigned sh = (unsigned)(d & 3) * 8u;
            const unsigned old = atomicAdd(&lcnt[d >> 2], 1u << sh);
            lrank[e] = (unsigned char)((old >> sh) & 0xffu);
        }
    } else {
        for (int e = e0 + t; e < e1; e += HT) {
            const int s = src[e];
            atomicAdd(&lcnt[s >> 2], 1u << ((unsigned)(s & 3) * 8u));
        }
    }
    __syncthreads();
    unsigned* g = (is_dst ? partial_in : partial_out) + (size_t)b * W;
    for (int i = t; i < W; i += HT) g[i] = lcnt[i];
}

// ---------------------------------------------------------------------------
// Reduce 128 partials per node-word (byte-parallel; totals < 256).
// ---------------------------------------------------------------------------
__global__ __launch_bounds__(256) void reduce_hist_kernel(const unsigned* __restrict__ partial_out,
                                                          const unsigned* __restrict__ partial_in,
                                                          unsigned* __restrict__ offs_in,
                                                          int* __restrict__ cnt_out,
                                                          int* __restrict__ cnt_in,
                                                          int W, int n, int nbW) {
    const bool is_dst = ((int)blockIdx.x < nbW);
    const int w = (is_dst ? blockIdx.x : (blockIdx.x - nbW)) * 256 + threadIdx.x;
    if (w >= W) return;
    unsigned run = 0;
    if (is_dst) {
#pragma unroll 16
        for (int b = 0; b < HB; ++b) {
            const unsigned c = partial_in[(size_t)b * W + w];
            offs_in[(size_t)b * W + w] = run;
            run += c;
        }
    } else {
#pragma unroll 16
        for (int b = 0; b < HB; ++b) run += partial_out[(size_t)b * W + w];
    }
    int* cnt = is_dst ? cnt_in : cnt_out;
    const int n0 = w * 4;
    const int4 c4 = make_int4((int)(run & 0xffu), (int)((run >> 8) & 0xffu),
                              (int)((run >> 16) & 0xffu), (int)((run >> 24) & 0xffu));
    if (n0 + 3 < n) {
        *(int4*)&cnt[n0] = c4;
    } else {
        const int* cp = &c4.x;
        for (int i = 0; i < 4 && n0 + i < n; ++i) cnt[n0 + i] = cp[i];
    }
}

// ---------------------------------------------------------------------------
// Exclusive scan stage 1.
// ---------------------------------------------------------------------------
__global__ __launch_bounds__(1024) void scan_block_kernel(const int* __restrict__ deg,
                                                          int* __restrict__ rp,
                                                          int* __restrict__ bsum, int n) {
    __shared__ int wsum[16];
    const int t = threadIdx.x;
    const int lane = t & 63;
    const int wid = t >> 6;
    const int i = blockIdx.x * 1024 + t;
    const int v = (i < n) ? deg[i] : 0;
    int s = v;
#pragma unroll
    for (int off = 1; off < 64; off <<= 1) {
        int u = __shfl_up(s, off, 64);
        if (lane >= off) s += u;
    }
    if (lane == 63) wsum[wid] = s;
    __syncthreads();
    if (wid == 0) {
        int ws = (lane < 16) ? wsum[lane] : 0;
#pragma unroll
        for (int off = 1; off < 16; off <<= 1) {
            int u = __shfl_up(ws, off, 64);
            if (lane >= off) ws += u;
        }
        if (lane < 16) wsum[lane] = ws;
    }
    __syncthreads();
    const int excl = s - v + ((wid > 0) ? wsum[wid - 1] : 0);
    if (i < n) rp[i] = excl;
    if (t == 0) bsum[blockIdx.x] = wsum[15];
}

// ---------------------------------------------------------------------------
// Stage 2 fused with norms; rp[n]=E known a priori.
// ---------------------------------------------------------------------------
__global__ __launch_bounds__(1024) void finalize_kernel(int* __restrict__ rp,
                                                        const int* __restrict__ bsum,
                                                        const int* __restrict__ cnt_out,
                                                        const int* __restrict__ cnt_in,
                                                        float* __restrict__ onorm,
                                                        float* __restrict__ inorm,
                                                        int n, int nb, int nE) {
    __shared__ int prefix_s;
    const int t = threadIdx.x;
    if (t < 64) {
        int v = (t < nb && t < (int)blockIdx.x) ? bsum[t] : 0;
#pragma unroll
        for (int off = 1; off < 64; off <<= 1) v += __shfl_xor(v, off, 64);
        if (t == 0) prefix_s = v;
    }
    __syncthreads();
    const int i = blockIdx.x * 1024 + t;
    if (i < n) {
        rp[i] += prefix_s;
        onorm[i] = rsqrtf(fmaxf((float)cnt_out[i], 1.0f));
        inorm[i] = rsqrtf(fmaxf((float)cnt_in[i], 1.0f));
    }
    if (blockIdx.x == 0 && t == 0) rp[n] = nE;
}

// ---------------------------------------------------------------------------
// FUSED: GEMM1 (y1 = (x@W1)*onorm -> fp16 SLICED layout) + atomic-free CSR
// fill. Fill blocks carry NO LDS so they keep full wave residency.
// ---------------------------------------------------------------------------
__global__ __launch_bounds__(1024) void gemm1_fill_kernel(
    const float* __restrict__ x, const _Float16* __restrict__ wt,
    const float* __restrict__ onorm, __half* __restrict__ y1, int nrows,
    const int* __restrict__ src, const int* __restrict__ dst,
    const unsigned char* __restrict__ lrank, const unsigned* __restrict__ offs_in,
    const int* __restrict__ rp, int* __restrict__ srcs_sorted,
    int nE, int epb, int W, int nGemmBlocks) {
    __shared__ _Float16 sA[128 * 136];
    __shared__ _Float16 sB[128 * 136];
    const int t = threadIdx.x;

    if ((int)blockIdx.x >= nGemmBlocks) {
        // ---- fill role: one edge per thread ----
        const int e = (blockIdx.x - nGemmBlocks) * 1024 + t;
        if (e < nE) {
            const int d = dst[e];
            const int b = e / epb;
            const unsigned off =
                (offs_in[(size_t)b * W + (d >> 2)] >> ((unsigned)(d & 3) * 8u)) & 0xffu;
            srcs_sorted[rp[d] + (int)off + (int)lrank[e]] = src[e];
        }
        return;
    }

    // ---- GEMM role: 128x128 tile, 16 waves ----
    const int row0 = blockIdx.x * 128;
    const int rr = t >> 4;      // 64 staging rows per pass
    const int c8 = t & 15;
#pragma unroll
    for (int pass = 0; pass < 2; ++pass) {
        const int row = pass * 64 + rr;
        *(float4*)&sB[row * 136 + c8 * 8] = *(const float4*)&wt[(size_t)row * D + c8 * 8];
        const int grow = row0 + row;
        float4 u0 = make_float4(0.f, 0.f, 0.f, 0.f);
        float4 u1 = u0;
        if (grow < nrows) {
            const float* ap = x + (size_t)grow * D + c8 * 8;
            u0 = ((const float4*)ap)[0];
            u1 = ((const float4*)ap)[1];
        }
        v8h hv;
        hv[0] = (_Float16)u0.x; hv[1] = (_Float16)u0.y;
        hv[2] = (_Float16)u0.z; hv[3] = (_Float16)u0.w;
        hv[4] = (_Float16)u1.x; hv[5] = (_Float16)u1.y;
        hv[6] = (_Float16)u1.z; hv[7] = (_Float16)u1.w;
        *(v8h*)&sA[row * 136 + c8 * 8] = hv;
    }
    __syncthreads();

    const int w = t >> 6;       // 16 waves
    const int lane = t & 63;
    const int m16 = lane & 15;
    const int quad = lane >> 4;
    const int rt = w >> 1;      // row-tile 0..7
    const int ch = w & 1;       // col half 0..1

    v4f c[4];
#pragma unroll
    for (int ct = 0; ct < 4; ++ct) c[ct] = (v4f){0.f, 0.f, 0.f, 0.f};

#pragma unroll
    for (int ks = 0; ks < 4; ++ks) {
        const v8h a = *(const v8h*)&sA[(rt * 16 + m16) * 136 + ks * 32 + quad * 8];
#pragma unroll
        for (int ct = 0; ct < 4; ++ct) {
            const v8h b = *(const v8h*)&sB[((ch * 4 + ct) * 16 + m16) * 136 + ks * 32 + quad * 8];
            c[ct] = __builtin_amdgcn_mfma_f32_16x16x32_f16(a, b, c[ct], 0, 0, 0);
        }
    }

#pragma unroll
    for (int r = 0; r < 4; ++r) {
        const int row = row0 + rt * 16 + quad * 4 + r;
        if (row < nrows) {
            const float osc = onorm[row];
#pragma unroll
            for (int ct = 0; ct < 4; ++ct) {
                const int col = (ch * 4 + ct) * 16 + m16;
                y1[(size_t)(col >> 5) * nrows * 32 + (size_t)row * 32 + (col & 31)] =
                    __float2half(c[ct][r] * osc);
            }
        }
    }
}

// ---------------------------------------------------------------------------
// Aggregation v3: sliced gather with R11's per-wave shape restored.
// Wave = 4 nodes x 4 edge slots x 4 chunks (16B) over ONE 32-col slice.
// Per iteration: 16 edges, 4 independent gather instrs in flight (4KB/wave,
// matching the R11-proven MLP). Wave count ~50k (same as R11).
// Slice tables are contiguous 3.2MB regions -> per-XCD L2-resident via the
// blockIdx%8 -> XCD round-robin pinning (slice = xcd&3, node-half = xcd>>2).
// srcs index reads are non-temporal (protect slice residency); output stores
// non-temporal (produced cross-XCD, never re-read by this XCD).
// ---------------------------------------------------------------------------
template <bool EPI>
__global__ __launch_bounds__(256) void aggregate_kernel(const __half* __restrict__ xh,
                                                        const float* __restrict__ onorm,
                                                        const float* __restrict__ inorm,
                                                        const float* __restrict__ bias,
                                                        const int* __restrict__ rp,
                                                        const int* __restrict__ srcs,
                                                        __half* __restrict__ agg,
                                                        int n_nodes, int halfsize) {
    const unsigned b = blockIdx.x;
    const int xcd = (int)(b & 7u);            // blockIdx%8 -> XCD
    const int slice = xcd & 3;                // 32-col slice (XCDs s, s+4 share)
    const int half = xcd >> 2;                // node half
    const int grp = (int)(b >> 3);
    const int t = threadIdx.x;
    const int wv = t >> 6;
    const int lane = t & 63;
    const int ns = lane >> 4;                 // node-sub 0..3
    const int rg = (lane >> 2) & 3;           // edge slot 0..3
    const int c4 = lane & 3;                  // 16B chunk 0..3 of the 64B row
    const int node = half * halfsize + grp * 16 + wv * 4 + ns;
    const int nhi = min(n_nodes, (half + 1) * halfsize);
    const bool vn = node < nhi;
    const __half* xs = xh + (size_t)slice * n_nodes * 32;

    int e = vn ? rp[node] + rg : 0;
    const int e1 = vn ? rp[node + 1] : 0;

    float acc0[8], acc1[8];
#pragma unroll
    for (int j = 0; j < 8; ++j) { acc0[j] = 0.f; acc1[j] = 0.f; }

    auto accum = [&](float* acc, const H8 v) {
#pragma unroll
        for (int j = 0; j < 4; ++j) {
            acc[2 * j]     += __low2float(v.h[j]);
            acc[2 * j + 1] += __high2float(v.h[j]);
        }
    };

    while (__any(e < e1)) {
        const bool p0 = e < e1;
        const bool p1 = e + 4 < e1;
        const bool p2 = e + 8 < e1;
        const bool p3 = e + 12 < e1;
        int s0 = 0, s1 = 0, s2 = 0, s3 = 0;
        if (p0) s0 = __builtin_nontemporal_load(srcs + e);
        if (p1) s1 = __builtin_nontemporal_load(srcs + e + 4);
        if (p2) s2 = __builtin_nontemporal_load(srcs + e + 8);
        if (p3) s3 = __builtin_nontemporal_load(srcs + e + 12);
        const H8 v0 = ((const H8*)(xs + (size_t)s0 * 32))[c4];
        const H8 v1 = ((const H8*)(xs + (size_t)s1 * 32))[c4];
        const H8 v2 = ((const H8*)(xs + (size_t)s2 * 32))[c4];
        const H8 v3 = ((const H8*)(xs + (size_t)s3 * 32))[c4];
        if (p0) accum(acc0, v0);
        if (p1) accum(acc1, v1);
        if (p2) accum(acc0, v2);
        if (p3) accum(acc1, v3);
        e += 16;
    }

    float r[8];
#pragma unroll
    for (int j = 0; j < 8; ++j) r[j] = acc0[j] + acc1[j];
#pragma unroll
    for (int off = 4; off <= 8; off <<= 1)     // reduce over the 4 edge slots
#pragma unroll
        for (int j = 0; j < 8; ++j) r[j] += __shfl_xor(r[j], off, 64);

    if (rg == 0 && vn) {
        if (EPI) {
            const float inm = inorm[node];
            const float onm = onorm[node];
            const float4 bv0 = ((const float4*)bias)[slice * 8 + c4 * 2];
            const float4 bv1 = ((const float4*)bias)[slice * 8 + c4 * 2 + 1];
            const float* bp0 = &bv0.x;
            const float* bp1 = &bv1.x;
#pragma unroll
            for (int j = 0; j < 4; ++j) {
                r[j]     = fmaxf(fmaf(r[j],     inm, bp0[j]), 0.f) * onm;
                r[j + 4] = fmaxf(fmaf(r[j + 4], inm, bp1[j]), 0.f) * onm;
            }
        }
        H8 h;
#pragma unroll
        for (int j = 0; j < 4; ++j) h.h[j] = __floats2half2_rn(r[2 * j], r[2 * j + 1]);
        v4i* op = (v4i*)(agg + (size_t)slice * n_nodes * 32 + (size_t)node * 32) + c4;
        __builtin_nontemporal_store(*(const v4i*)&h, op);
    }
}

// ---------------------------------------------------------------------------
// MFMA GEMM for layers 2/3 (R9-proven math). A is fp16 SLICED layout; OUT16
// stores sliced (feeds next aggregate); fp32 path stores row-major (d_out).
// ---------------------------------------------------------------------------
template <bool FULL, bool RELU, bool OSCALE, bool OUT16>
__global__ __launch_bounds__(256) void gemm_mfma_kernel(const __half* __restrict__ Ah,
                                                        const _Float16* __restrict__ Wt,
                                                        const float* __restrict__ bias,
                                                        const float* __restrict__ inorm,
                                                        const float* __restrict__ onorm,
                                                        void* __restrict__ outv, int nrows) {
    __shared__ _Float16 sA[128 * 136];
    __shared__ _Float16 sB[128 * 136];
    const int t = threadIdx.x;
    const int row0 = blockIdx.x * 128;
    const int rr = t >> 4;
    const int c8 = t & 15;

#pragma unroll
    for (int pass = 0; pass < 8; ++pass) {
        const int row = pass * 16 + rr;
        *(float4*)&sB[row * 136 + c8 * 8] = *(const float4*)&Wt[(size_t)row * D + c8 * 8];
        const int grow = row0 + row;
        float4 v = make_float4(0.f, 0.f, 0.f, 0.f);
        if (grow < nrows)
            v = *(const float4*)((const _Float16*)Ah + (size_t)(c8 >> 2) * nrows * 32 +
                                 (size_t)grow * 32 + (c8 & 3) * 8);
        *(float4*)&sA[row * 136 + c8 * 8] = v;
    }
    __syncthreads();

    const int w = t >> 6;
    const int lane = t & 63;
    const int m16 = lane & 15;
    const int quad = lane >> 4;

    v4f c[2][8];
#pragma unroll
    for (int rt = 0; rt < 2; ++rt)
#pragma unroll
        for (int ct = 0; ct < 8; ++ct) c[rt][ct] = (v4f){0.f, 0.f, 0.f, 0.f};

#pragma unroll
    for (int ks = 0; ks < 4; ++ks) {
        v8h afr[2], bfr[8];
#pragma unroll
        for (int rt = 0; rt < 2; ++rt)
            afr[rt] = *(const v8h*)&sA[(w * 32 + rt * 16 + m16) * 136 + ks * 32 + quad * 8];
#pragma unroll
        for (int ct = 0; ct < 8; ++ct)
            bfr[ct] = *(const v8h*)&sB[(ct * 16 + m16) * 136 + ks * 32 + quad * 8];
#pragma unroll
        for (int rt = 0; rt < 2; ++rt)
#pragma unroll
            for (int ct = 0; ct < 8; ++ct)
                c[rt][ct] = __builtin_amdgcn_mfma_f32_16x16x32_f16(afr[rt], bfr[ct], c[rt][ct], 0, 0, 0);
    }

#pragma unroll
    for (int rt = 0; rt < 2; ++rt) {
#pragma unroll
        for (int r = 0; r < 4; ++r) {
            const int row = row0 + w * 32 + rt * 16 + quad * 4 + r;
            if (row < nrows) {
                const float inm = FULL ? inorm[row] : 1.0f;
                const float osc = OSCALE ? onorm[row] : 1.0f;
#pragma unroll
                for (int ct = 0; ct < 8; ++ct) {
                    const int col = ct * 16 + m16;
                    float v = c[rt][ct][r];
                    if (FULL) v = fmaf(v, inm, bias[col]);
                    if (RELU) v = fmaxf(v, 0.f);
                    if (OSCALE) v *= osc;
                    if (OUT16)
                        ((__half*)outv)[(size_t)(col >> 5) * nrows * 32 +
                                        (size_t)row * 32 + (col & 31)] = __float2half(v);
                    else
                        ((float*)outv)[(size_t)row * D + col] = v;
                }
            }
        }
    }
}

// ---------------------------------------------------------------------------
// Host launch
// ---------------------------------------------------------------------------
extern "C" void kernel_launch(void* const* d_in, const int* in_sizes, int n_in,
                              void* d_out, int out_size, void* d_ws, size_t ws_size,
                              hipStream_t stream) {
    const float* x   = (const float*)d_in[0];
    const int*   src = (const int*)d_in[1];
    const int*   dst = (const int*)d_in[2];
    const float* W1  = (const float*)d_in[3];
    const float* b1  = (const float*)d_in[4];
    const float* W2  = (const float*)d_in[5];
    const float* b2  = (const float*)d_in[6];
    const float* W3  = (const float*)d_in[7];
    const float* b3  = (const float*)d_in[8];

    const int N = in_sizes[0] / D;   // 50000
    const int E = in_sizes[1];       // 800000

    char* p = (char*)d_ws;
    auto alloc = [&](size_t bytes) -> void* {
        void* r = (void*)p;
        p += (bytes + 255) & ~(size_t)255;
        return r;
    };
    int*           cnt_out = (int*)alloc((size_t)N * 4);
    int*           cnt_in  = (int*)alloc((size_t)N * 4);
    int*           rp      = (int*)alloc((size_t)(N + 1) * 4);
    int*           bsum    = (int*)alloc(1024 * 4);
    float*         onorm   = (float*)alloc((size_t)N * 4);
    float*         inorm   = (float*)alloc((size_t)N * 4);
    int*           srcs    = (int*)alloc((size_t)E * 4);
    unsigned char* lrank   = (unsigned char*)alloc((size_t)E);
    _Float16*      wt      = (_Float16*)alloc((size_t)3 * D * D * 2);
    __half*        hbuf0   = (__half*)alloc((size_t)N * D * 2);  // y1, then h2 (sliced)
    __half*        hbuf1   = (__half*)alloc((size_t)N * D * 2);  // h1 (sliced)
    char*          scratch = (char*)alloc((size_t)3 * HB * ((N + 3) / 4) * 4);  // 19.2MB

    const int W = (N + 3) / 4;              // 12500 packed histogram words
    const int epb = (E + HB - 1) / HB;      // 6250 edges per histogram block
    unsigned* partial_in  = (unsigned*)scratch;
    unsigned* partial_out = partial_in + (size_t)HB * W;
    unsigned* offs_in     = partial_out + (size_t)HB * W;
    __half*   abuf        = (__half*)scratch;                  // a2, a3 (fp16, sliced)
    float*    outf        = (float*)d_out;

    const int nb = (N + 1023) / 1024;       // 49
    const int nbW = (W + 255) / 256;        // 49
    const int gemmGrid = (N + 127) / 128;   // 391
    const int fillGrid = (E + 1023) / 1024; // 782
    // sliced aggregate: block = 16 nodes x 1 slice; blockIdx%8 -> XCD pins
    // (slice, node-half). grid = 8 * ceil(halfsize/16).
    const int halfsize = (N + 1) / 2;                    // 25000
    const int aggGrid = 8 * ((halfsize + 15) / 16);      // 12504 blocks

    // Graph build (hist + W-prep merged); no global atomics, no memset
    hist_kernel<<<2 * HB + 3, HT, 0, stream>>>(src, dst, partial_out, partial_in, lrank,
                                               W1, W2, W3, wt, E, W, epb);
    reduce_hist_kernel<<<2 * nbW, 256, 0, stream>>>(partial_out, partial_in, offs_in,
                                                    cnt_out, cnt_in, W, N, nbW);
    scan_block_kernel<<<nb, 1024, 0, stream>>>(cnt_in, rp, bsum, N);
    finalize_kernel<<<nb, 1024, 0, stream>>>(rp, bsum, cnt_out, cnt_in, onorm, inorm, N, nb, E);

    // Fused: GEMM1 (y1 = (x@W1)*onorm -> fp16 sliced) + CSR fill
    gemm1_fill_kernel<<<gemmGrid + fillGrid, 1024, 0, stream>>>(
        x, wt, onorm, hbuf0, N,
        src, dst, lrank, offs_in, rp, srcs, E, epb, W, gemmGrid);

    // Layer 1 aggregate + full epilogue -> h1 fp16 (sliced)
    aggregate_kernel<true><<<aggGrid, 256, 0, stream>>>(
        hbuf0, onorm, inorm, b1, rp, srcs, hbuf1, N, halfsize);
    // Layer 2: a2 = agg(h1) fp16 sliced; h2 = relu((a2@W2)*inorm+b2)*onorm -> fp16 sliced
    aggregate_kernel<false><<<aggGrid, 256, 0, stream>>>(
        hbuf1, onorm, inorm, b2, rp, srcs, abuf, N, halfsize);
    gemm_mfma_kernel<true, true, true, true><<<gemmGrid, 256, 0, stream>>>(
        abuf, wt + (size_t)D * D, b2, inorm, onorm, hbuf0, N);
    // Layer 3: a3 = agg(h2) fp16 sliced; out = (a3@W3)*inorm+b3 -> fp32 d_out (row-major)
    aggregate_kernel<false><<<aggGrid, 256, 0, stream>>>(
        hbuf0, onorm, inorm, b3, rp, srcs, abuf, N, halfsize);
    gemm_mfma_kernel<true, false, false, false><<<gemmGrid, 256, 0, stream>>>(
        abuf, wt + (size_t)2 * D * D, b3, inorm, onorm, outf, N);
}

// Round 5
// 259.515 us; speedup vs baseline: 1.5115x; 1.1083x over previous
//
#include <hip/hip_runtime.h>
#include <hip/hip_fp16.h>

#define D 128
#define HB 128        // histogram blocks per role (edge-partitioned)
#define HT 1024       // threads per histogram block
#define WMAX 12800    // LDS histogram words (4 nodes/word, byte counters)

struct alignas(16) H8 { __half2 h[4]; };
typedef _Float16 v8h __attribute__((ext_vector_type(8)));
typedef float v4f __attribute__((ext_vector_type(4)));
typedef int v4i __attribute__((ext_vector_type(4)));

// ---------------------------------------------------------------------------
// SLICED feature layout (R14-proven): fp16 intermediates stored as
// [slice 0..3][node][32 cols]; each slice 3.2MB < 4MiB per-XCD L2.
// FETCH for aggregate: 205MB (row-major) -> 21MB (sliced, R15 measured).
//   addr(node, col) = (col>>5)*N*32 + node*32 + (col&31)   [in halves]
// ---------------------------------------------------------------------------

// ---------------------------------------------------------------------------
// Edge-partitioned LDS histogram (R8-proven) + merged W-prep role.
// ---------------------------------------------------------------------------
__global__ __launch_bounds__(HT) void hist_kernel(const int* __restrict__ src,
                                                  const int* __restrict__ dst,
                                                  unsigned* __restrict__ partial_out,
                                                  unsigned* __restrict__ partial_in,
                                                  unsigned char* __restrict__ lrank,
                                                  const float* __restrict__ W1,
                                                  const float* __restrict__ W2,
                                                  const float* __restrict__ W3,
                                                  _Float16* __restrict__ wt,
                                                  int nE, int W, int epb) {
    const int t = threadIdx.x;
    if ((int)blockIdx.x >= 2 * HB) {                 // W-prep role
        const int l = blockIdx.x - 2 * HB;
        const float* Wsrc = (l == 0) ? W1 : ((l == 1) ? W2 : W3);
        _Float16* o = wt + (size_t)l * D * D;
        for (int i = t; i < D * D; i += HT) {
            const int k = i >> 7, n = i & 127;
            o[n * D + k] = (_Float16)Wsrc[i];
        }
        return;
    }
    __shared__ unsigned lcnt[WMAX];
    const bool is_dst = (blockIdx.x < HB);
    const int b = is_dst ? blockIdx.x : (blockIdx.x - HB);
    for (int i = t; i < W; i += HT) lcnt[i] = 0;
    __syncthreads();
    const int e0 = b * epb;
    const int e1 = min(nE, e0 + epb);
    if (is_dst) {
        for (int e = e0 + t; e < e1; e += HT) {
            const int d = dst[e];
            const unsigned sh = (unsigned)(d & 3) * 8u;
            const unsigned old = atomicAdd(&lcnt[d >> 2], 1u << sh);
            lrank[e] = (unsigned char)((old >> sh) & 0xffu);
        }
    } else {
        for (int e = e0 + t; e < e1; e += HT) {
            const int s = src[e];
            atomicAdd(&lcnt[s >> 2], 1u << ((unsigned)(s & 3) * 8u));
        }
    }
    __syncthreads();
    unsigned* g = (is_dst ? partial_in : partial_out) + (size_t)b * W;
    for (int i = t; i < W; i += HT) g[i] = lcnt[i];
}

// ---------------------------------------------------------------------------
// Reduce 128 partials per node-word (byte-parallel; totals < 256).
// ---------------------------------------------------------------------------
__global__ __launch_bounds__(256) void reduce_hist_kernel(const unsigned* __restrict__ partial_out,
                                                          const unsigned* __restrict__ partial_in,
                                                          unsigned* __restrict__ offs_in,
                                                          int* __restrict__ cnt_out,
                                                          int* __restrict__ cnt_in,
                                                          int W, int n, int nbW) {
    const bool is_dst = ((int)blockIdx.x < nbW);
    const int w = (is_dst ? blockIdx.x : (blockIdx.x - nbW)) * 256 + threadIdx.x;
    if (w >= W) return;
    unsigned run = 0;
    if (is_dst) {
#pragma unroll 16
        for (int b = 0; b < HB; ++b) {
            const unsigned c = partial_in[(size_t)b * W + w];
            offs_in[(size_t)b * W + w] = run;
            run += c;
        }
    } else {
#pragma unroll 16
        for (int b = 0; b < HB; ++b) run += partial_out[(size_t)b * W + w];
    }
    int* cnt = is_dst ? cnt_in : cnt_out;
    const int n0 = w * 4;
    const int4 c4 = make_int4((int)(run & 0xffu), (int)((run >> 8) & 0xffu),
                              (int)((run >> 16) & 0xffu), (int)((run >> 24) & 0xffu));
    if (n0 + 3 < n) {
        *(int4*)&cnt[n0] = c4;
    } else {
        const int* cp = &c4.x;
        for (int i = 0; i < 4 && n0 + i < n; ++i) cnt[n0 + i] = cp[i];
    }
}

// ---------------------------------------------------------------------------
// Exclusive scan stage 1.
// ---------------------------------------------------------------------------
__global__ __launch_bounds__(1024) void scan_block_kernel(const int* __restrict__ deg,
                                                          int* __restrict__ rp,
                                                          int* __restrict__ bsum, int n) {
    __shared__ int wsum[16];
    const int t = threadIdx.x;
    const int lane = t & 63;
    const int wid = t >> 6;
    const int i = blockIdx.x * 1024 + t;
    const int v = (i < n) ? deg[i] : 0;
    int s = v;
#pragma unroll
    for (int off = 1; off < 64; off <<= 1) {
        int u = __shfl_up(s, off, 64);
        if (lane >= off) s += u;
    }
    if (lane == 63) wsum[wid] = s;
    __syncthreads();
    if (wid == 0) {
        int ws = (lane < 16) ? wsum[lane] : 0;
#pragma unroll
        for (int off = 1; off < 16; off <<= 1) {
            int u = __shfl_up(ws, off, 64);
            if (lane >= off) ws += u;
        }
        if (lane < 16) wsum[lane] = ws;
    }
    __syncthreads();
    const int excl = s - v + ((wid > 0) ? wsum[wid - 1] : 0);
    if (i < n) rp[i] = excl;
    if (t == 0) bsum[blockIdx.x] = wsum[15];
}

// ---------------------------------------------------------------------------
// Stage 2 fused with norms; rp[n]=E known a priori.
// ---------------------------------------------------------------------------
__global__ __launch_bounds__(1024) void finalize_kernel(int* __restrict__ rp,
                                                        const int* __restrict__ bsum,
                                                        const int* __restrict__ cnt_out,
                                                        const int* __restrict__ cnt_in,
                                                        float* __restrict__ onorm,
                                                        float* __restrict__ inorm,
                                                        int n, int nb, int nE) {
    __shared__ int prefix_s;
    const int t = threadIdx.x;
    if (t < 64) {
        int v = (t < nb && t < (int)blockIdx.x) ? bsum[t] : 0;
#pragma unroll
        for (int off = 1; off < 64; off <<= 1) v += __shfl_xor(v, off, 64);
        if (t == 0) prefix_s = v;
    }
    __syncthreads();
    const int i = blockIdx.x * 1024 + t;
    if (i < n) {
        rp[i] += prefix_s;
        onorm[i] = rsqrtf(fmaxf((float)cnt_out[i], 1.0f));
        inorm[i] = rsqrtf(fmaxf((float)cnt_in[i], 1.0f));
    }
    if (blockIdx.x == 0 && t == 0) rp[n] = nE;
}

// ---------------------------------------------------------------------------
// FUSED: GEMM1 (y1 = (x@W1)*onorm -> fp16 SLICED layout) + atomic-free CSR
// fill. Fill blocks carry NO LDS so they keep full wave residency.
// ---------------------------------------------------------------------------
__global__ __launch_bounds__(1024) void gemm1_fill_kernel(
    const float* __restrict__ x, const _Float16* __restrict__ wt,
    const float* __restrict__ onorm, __half* __restrict__ y1, int nrows,
    const int* __restrict__ src, const int* __restrict__ dst,
    const unsigned char* __restrict__ lrank, const unsigned* __restrict__ offs_in,
    const int* __restrict__ rp, int* __restrict__ srcs_sorted,
    int nE, int epb, int W, int nGemmBlocks) {
    __shared__ _Float16 sA[128 * 136];
    __shared__ _Float16 sB[128 * 136];
    const int t = threadIdx.x;

    if ((int)blockIdx.x >= nGemmBlocks) {
        // ---- fill role: one edge per thread ----
        const int e = (blockIdx.x - nGemmBlocks) * 1024 + t;
        if (e < nE) {
            const int d = dst[e];
            const int b = e / epb;
            const unsigned off =
                (offs_in[(size_t)b * W + (d >> 2)] >> ((unsigned)(d & 3) * 8u)) & 0xffu;
            srcs_sorted[rp[d] + (int)off + (int)lrank[e]] = src[e];
        }
        return;
    }

    // ---- GEMM role: 128x128 tile, 16 waves ----
    const int row0 = blockIdx.x * 128;
    const int rr = t >> 4;      // 64 staging rows per pass
    const int c8 = t & 15;
#pragma unroll
    for (int pass = 0; pass < 2; ++pass) {
        const int row = pass * 64 + rr;
        *(float4*)&sB[row * 136 + c8 * 8] = *(const float4*)&wt[(size_t)row * D + c8 * 8];
        const int grow = row0 + row;
        float4 u0 = make_float4(0.f, 0.f, 0.f, 0.f);
        float4 u1 = u0;
        if (grow < nrows) {
            const float* ap = x + (size_t)grow * D + c8 * 8;
            u0 = ((const float4*)ap)[0];
            u1 = ((const float4*)ap)[1];
        }
        v8h hv;
        hv[0] = (_Float16)u0.x; hv[1] = (_Float16)u0.y;
        hv[2] = (_Float16)u0.z; hv[3] = (_Float16)u0.w;
        hv[4] = (_Float16)u1.x; hv[5] = (_Float16)u1.y;
        hv[6] = (_Float16)u1.z; hv[7] = (_Float16)u1.w;
        *(v8h*)&sA[row * 136 + c8 * 8] = hv;
    }
    __syncthreads();

    const int w = t >> 6;       // 16 waves
    const int lane = t & 63;
    const int m16 = lane & 15;
    const int quad = lane >> 4;
    const int rt = w >> 1;      // row-tile 0..7
    const int ch = w & 1;       // col half 0..1

    v4f c[4];
#pragma unroll
    for (int ct = 0; ct < 4; ++ct) c[ct] = (v4f){0.f, 0.f, 0.f, 0.f};

#pragma unroll
    for (int ks = 0; ks < 4; ++ks) {
        const v8h a = *(const v8h*)&sA[(rt * 16 + m16) * 136 + ks * 32 + quad * 8];
#pragma unroll
        for (int ct = 0; ct < 4; ++ct) {
            const v8h b = *(const v8h*)&sB[((ch * 4 + ct) * 16 + m16) * 136 + ks * 32 + quad * 8];
            c[ct] = __builtin_amdgcn_mfma_f32_16x16x32_f16(a, b, c[ct], 0, 0, 0);
        }
    }

#pragma unroll
    for (int r = 0; r < 4; ++r) {
        const int row = row0 + rt * 16 + quad * 4 + r;
        if (row < nrows) {
            const float osc = onorm[row];
#pragma unroll
            for (int ct = 0; ct < 4; ++ct) {
                const int col = (ch * 4 + ct) * 16 + m16;
                y1[(size_t)(col >> 5) * nrows * 32 + (size_t)row * 32 + (col & 31)] =
                    __float2half(c[ct][r] * osc);
            }
        }
    }
}

// ---------------------------------------------------------------------------
// Aggregation v4: sliced gather, 8-deep prefetched edge unroll.
// R15 post-mortem: sliced residency proven (FETCH 205->21MB) but dispatch
// stuck at 45us = latency/issue-bound (hbm 9%, VALU 41%, occ 61%). The
// per-iteration chain srcs(L3 ~600cy) -> gather(L2 ~300cy) was paid 1-2x
// per wave with only 4 loads in flight, and accumulate cost 16 VALU/16B.
// Fix: (a) issue ALL 8 srcs loads up front (exec-masked, so masked lanes
// issue nothing), then 8 UNCONDITIONAL gathers (s[k]=0 default -> row 0 is
// L1-hot, harmless) so both latencies are paid once per wave with 8 gathers
// (128B/lane) in flight; covers deg<=32 in one shot (Poisson-16: >99.9% of
// nodes), rare tail loop for the rest. (b) fmaf(float(h),1.0f,acc) matches
// clang's mad-mix pattern -> v_fma_mix_f32, halving accumulate VALU.
// ---------------------------------------------------------------------------
template <bool EPI>
__global__ __launch_bounds__(256) void aggregate_kernel(const __half* __restrict__ xh,
                                                        const float* __restrict__ onorm,
                                                        const float* __restrict__ inorm,
                                                        const float* __restrict__ bias,
                                                        const int* __restrict__ rp,
                                                        const int* __restrict__ srcs,
                                                        __half* __restrict__ agg,
                                                        int n_nodes, int halfsize) {
    const unsigned b = blockIdx.x;
    const int xcd = (int)(b & 7u);            // blockIdx%8 -> XCD
    const int slice = xcd & 3;                // 32-col slice (XCDs s, s+4 share)
    const int half = xcd >> 2;                // node half
    const int grp = (int)(b >> 3);
    const int t = threadIdx.x;
    const int wv = t >> 6;
    const int lane = t & 63;
    const int ns = lane >> 4;                 // node-sub 0..3
    const int rg = (lane >> 2) & 3;           // edge slot 0..3
    const int c4 = lane & 3;                  // 16B chunk 0..3 of the 64B row
    const int node = half * halfsize + grp * 16 + wv * 4 + ns;
    const int nhi = min(n_nodes, (half + 1) * halfsize);
    const bool vn = node < nhi;
    const __half* xs = xh + (size_t)slice * n_nodes * 32;

    const int e0 = vn ? rp[node] : 0;
    const int e1 = vn ? rp[node + 1] : 0;
    int e = e0 + rg;

    float acc[8];
#pragma unroll
    for (int j = 0; j < 8; ++j) acc[j] = 0.f;

    // ---- first pass: 8-deep, all loads issued before any use ----
    bool pr[8];
#pragma unroll
    for (int k = 0; k < 8; ++k) pr[k] = (e + 4 * k) < e1;
    int s[8];
#pragma unroll
    for (int k = 0; k < 8; ++k) {
        s[k] = 0;
        if (pr[k]) s[k] = __builtin_nontemporal_load(srcs + e + 4 * k);
    }
    H8 v[8];
#pragma unroll
    for (int k = 0; k < 8; ++k)
        v[k] = ((const H8*)(xs + (size_t)s[k] * 32))[c4];
#pragma unroll
    for (int k = 0; k < 8; ++k) {
        if (pr[k]) {
#pragma unroll
            for (int j = 0; j < 4; ++j) {
                acc[2 * j]     = fmaf(__low2float(v[k].h[j]),  1.0f, acc[2 * j]);
                acc[2 * j + 1] = fmaf(__high2float(v[k].h[j]), 1.0f, acc[2 * j + 1]);
            }
        }
    }
    e += 32;

    // ---- rare tail (deg > 32) ----
    while (__any(e < e1)) {
        bool q[4];
        int u[4];
#pragma unroll
        for (int k = 0; k < 4; ++k) {
            q[k] = (e + 4 * k) < e1;
            u[k] = 0;
            if (q[k]) u[k] = __builtin_nontemporal_load(srcs + e + 4 * k);
        }
        H8 w[4];
#pragma unroll
        for (int k = 0; k < 4; ++k)
            w[k] = ((const H8*)(xs + (size_t)u[k] * 32))[c4];
#pragma unroll
        for (int k = 0; k < 4; ++k) {
            if (q[k]) {
#pragma unroll
                for (int j = 0; j < 4; ++j) {
                    acc[2 * j]     = fmaf(__low2float(w[k].h[j]),  1.0f, acc[2 * j]);
                    acc[2 * j + 1] = fmaf(__high2float(w[k].h[j]), 1.0f, acc[2 * j + 1]);
                }
            }
        }
        e += 16;
    }

    float r[8];
#pragma unroll
    for (int j = 0; j < 8; ++j) r[j] = acc[j];
#pragma unroll
    for (int off = 4; off <= 8; off <<= 1)     // reduce over the 4 edge slots
#pragma unroll
        for (int j = 0; j < 8; ++j) r[j] += __shfl_xor(r[j], off, 64);

    if (rg == 0 && vn) {
        if (EPI) {
            const float inm = inorm[node];
            const float onm = onorm[node];
            const float4 bv0 = ((const float4*)bias)[slice * 8 + c4 * 2];
            const float4 bv1 = ((const float4*)bias)[slice * 8 + c4 * 2 + 1];
            const float* bp0 = &bv0.x;
            const float* bp1 = &bv1.x;
#pragma unroll
            for (int j = 0; j < 4; ++j) {
                r[j]     = fmaxf(fmaf(r[j],     inm, bp0[j]), 0.f) * onm;
                r[j + 4] = fmaxf(fmaf(r[j + 4], inm, bp1[j]), 0.f) * onm;
            }
        }
        H8 h;
#pragma unroll
        for (int j = 0; j < 4; ++j) h.h[j] = __floats2half2_rn(r[2 * j], r[2 * j + 1]);
        v4i* op = (v4i*)(agg + (size_t)slice * n_nodes * 32 + (size_t)node * 32) + c4;
        __builtin_nontemporal_store(*(const v4i*)&h, op);
    }
}

// ---------------------------------------------------------------------------
// MFMA GEMM for layers 2/3 (R9-proven math). A is fp16 SLICED layout; OUT16
// stores sliced (feeds next aggregate); fp32 path stores row-major (d_out).
// ---------------------------------------------------------------------------
template <bool FULL, bool RELU, bool OSCALE, bool OUT16>
__global__ __launch_bounds__(256) void gemm_mfma_kernel(const __half* __restrict__ Ah,
                                                        const _Float16* __restrict__ Wt,
                                                        const float* __restrict__ bias,
                                                        const float* __restrict__ inorm,
                                                        const float* __restrict__ onorm,
                                                        void* __restrict__ outv, int nrows) {
    __shared__ _Float16 sA[128 * 136];
    __shared__ _Float16 sB[128 * 136];
    const int t = threadIdx.x;
    const int row0 = blockIdx.x * 128;
    const int rr = t >> 4;
    const int c8 = t & 15;

#pragma unroll
    for (int pass = 0; pass < 8; ++pass) {
        const int row = pass * 16 + rr;
        *(float4*)&sB[row * 136 + c8 * 8] = *(const float4*)&Wt[(size_t)row * D + c8 * 8];
        const int grow = row0 + row;
        float4 v = make_float4(0.f, 0.f, 0.f, 0.f);
        if (grow < nrows)
            v = *(const float4*)((const _Float16*)Ah + (size_t)(c8 >> 2) * nrows * 32 +
                                 (size_t)grow * 32 + (c8 & 3) * 8);
        *(float4*)&sA[row * 136 + c8 * 8] = v;
    }
    __syncthreads();

    const int w = t >> 6;
    const int lane = t & 63;
    const int m16 = lane & 15;
    const int quad = lane >> 4;

    v4f c[2][8];
#pragma unroll
    for (int rt = 0; rt < 2; ++rt)
#pragma unroll
        for (int ct = 0; ct < 8; ++ct) c[rt][ct] = (v4f){0.f, 0.f, 0.f, 0.f};

#pragma unroll
    for (int ks = 0; ks < 4; ++ks) {
        v8h afr[2], bfr[8];
#pragma unroll
        for (int rt = 0; rt < 2; ++rt)
            afr[rt] = *(const v8h*)&sA[(w * 32 + rt * 16 + m16) * 136 + ks * 32 + quad * 8];
#pragma unroll
        for (int ct = 0; ct < 8; ++ct)
            bfr[ct] = *(const v8h*)&sB[(ct * 16 + m16) * 136 + ks * 32 + quad * 8];
#pragma unroll
        for (int rt = 0; rt < 2; ++rt)
#pragma unroll
            for (int ct = 0; ct < 8; ++ct)
                c[rt][ct] = __builtin_amdgcn_mfma_f32_16x16x32_f16(afr[rt], bfr[ct], c[rt][ct], 0, 0, 0);
    }

#pragma unroll
    for (int rt = 0; rt < 2; ++rt) {
#pragma unroll
        for (int r = 0; r < 4; ++r) {
            const int row = row0 + w * 32 + rt * 16 + quad * 4 + r;
            if (row < nrows) {
                const float inm = FULL ? inorm[row] : 1.0f;
                const float osc = OSCALE ? onorm[row] : 1.0f;
#pragma unroll
                for (int ct = 0; ct < 8; ++ct) {
                    const int col = ct * 16 + m16;
                    float v = c[rt][ct][r];
                    if (FULL) v = fmaf(v, inm, bias[col]);
                    if (RELU) v = fmaxf(v, 0.f);
                    if (OSCALE) v *= osc;
                    if (OUT16)
                        ((__half*)outv)[(size_t)(col >> 5) * nrows * 32 +
                                        (size_t)row * 32 + (col & 31)] = __float2half(v);
                    else
                        ((float*)outv)[(size_t)row * D + col] = v;
                }
            }
        }
    }
}

// ---------------------------------------------------------------------------
// Host launch
// ---------------------------------------------------------------------------
extern "C" void kernel_launch(void* const* d_in, const int* in_sizes, int n_in,
                              void* d_out, int out_size, void* d_ws, size_t ws_size,
                              hipStream_t stream) {
    const float* x   = (const float*)d_in[0];
    const int*   src = (const int*)d_in[1];
    const int*   dst = (const int*)d_in[2];
    const float* W1  = (const float*)d_in[3];
    const float* b1  = (const float*)d_in[4];
    const float* W2  = (const float*)d_in[5];
    const float* b2  = (const float*)d_in[6];
    const float* W3  = (const float*)d_in[7];
    const float* b3  = (const float*)d_in[8];

    const int N = in_sizes[0] / D;   // 50000
    const int E = in_sizes[1];       // 800000

    char* p = (char*)d_ws;
    auto alloc = [&](size_t bytes) -> void* {
        void* r = (void*)p;
        p += (bytes + 255) & ~(size_t)255;
        return r;
    };
    int*           cnt_out = (int*)alloc((size_t)N * 4);
    int*           cnt_in  = (int*)alloc((size_t)N * 4);
    int*           rp      = (int*)alloc((size_t)(N + 1) * 4);
    int*           bsum    = (int*)alloc(1024 * 4);
    float*         onorm   = (float*)alloc((size_t)N * 4);
    float*         inorm   = (float*)alloc((size_t)N * 4);
    int*           srcs    = (int*)alloc((size_t)E * 4);
    unsigned char* lrank   = (unsigned char*)alloc((size_t)E);
    _Float16*      wt      = (_Float16*)alloc((size_t)3 * D * D * 2);
    __half*        hbuf0   = (__half*)alloc((size_t)N * D * 2);  // y1, then h2 (sliced)
    __half*        hbuf1   = (__half*)alloc((size_t)N * D * 2);  // h1 (sliced)
    char*          scratch = (char*)alloc((size_t)3 * HB * ((N + 3) / 4) * 4);  // 19.2MB

    const int W = (N + 3) / 4;              // 12500 packed histogram words
    const int epb = (E + HB - 1) / HB;      // 6250 edges per histogram block
    unsigned* partial_in  = (unsigned*)scratch;
    unsigned* partial_out = partial_in + (size_t)HB * W;
    unsigned* offs_in     = partial_out + (size_t)HB * W;
    __half*   abuf        = (__half*)scratch;                  // a2, a3 (fp16, sliced)
    float*    outf        = (float*)d_out;

    const int nb = (N + 1023) / 1024;       // 49
    const int nbW = (W + 255) / 256;        // 49
    const int gemmGrid = (N + 127) / 128;   // 391
    const int fillGrid = (E + 1023) / 1024; // 782
    // sliced aggregate: block = 16 nodes x 1 slice; blockIdx%8 -> XCD pins
    // (slice, node-half). grid = 8 * ceil(halfsize/16).
    const int halfsize = (N + 1) / 2;                    // 25000
    const int aggGrid = 8 * ((halfsize + 15) / 16);      // 12504 blocks

    // Graph build (hist + W-prep merged); no global atomics, no memset
    hist_kernel<<<2 * HB + 3, HT, 0, stream>>>(src, dst, partial_out, partial_in, lrank,
                                               W1, W2, W3, wt, E, W, epb);
    reduce_hist_kernel<<<2 * nbW, 256, 0, stream>>>(partial_out, partial_in, offs_in,
                                                    cnt_out, cnt_in, W, N, nbW);
    scan_block_kernel<<<nb, 1024, 0, stream>>>(cnt_in, rp, bsum, N);
    finalize_kernel<<<nb, 1024, 0, stream>>>(rp, bsum, cnt_out, cnt_in, onorm, inorm, N, nb, E);

    // Fused: GEMM1 (y1 = (x@W1)*onorm -> fp16 sliced) + CSR fill
    gemm1_fill_kernel<<<gemmGrid + fillGrid, 1024, 0, stream>>>(
        x, wt, onorm, hbuf0, N,
        src, dst, lrank, offs_in, rp, srcs, E, epb, W, gemmGrid);

    // Layer 1 aggregate + full epilogue -> h1 fp16 (sliced)
    aggregate_kernel<true><<<aggGrid, 256, 0, stream>>>(
        hbuf0, onorm, inorm, b1, rp, srcs, hbuf1, N, halfsize);
    // Layer 2: a2 = agg(h1) fp16 sliced; h2 = relu((a2@W2)*inorm+b2)*onorm -> fp16 sliced
    aggregate_kernel<false><<<aggGrid, 256, 0, stream>>>(
        hbuf1, onorm, inorm, b2, rp, srcs, abuf, N, halfsize);
    gemm_mfma_kernel<true, true, true, true><<<gemmGrid, 256, 0, stream>>>(
        abuf, wt + (size_t)D * D, b2, inorm, onorm, hbuf0, N);
    // Layer 3: a3 = agg(h2) fp16 sliced; out = (a3@W3)*inorm+b3 -> fp32 d_out (row-major)
    aggregate_kernel<false><<<aggGrid, 256, 0, stream>>>(
        hbuf0, onorm, inorm, b3, rp, srcs, abuf, N, halfsize);
    gemm_mfma_kernel<true, false, false, false><<<gemmGrid, 256, 0, stream>>>(
        abuf, wt + (size_t)2 * D * D, b3, inorm, onorm, outf, N);
}

// Round 6
// 239.286 us; speedup vs baseline: 1.6393x; 1.0845x over previous
//
#include <hip/hip_runtime.h>
#include <hip/hip_fp16.h>

#define D 128
#define HB 128        // histogram blocks per role (edge-partitioned)
#define HT 1024       // threads per histogram block
#define WMAX 12800    // LDS histogram words (4 nodes/word, byte counters)

struct alignas(16) H8 { __half2 h[4]; };
typedef _Float16 v8h __attribute__((ext_vector_type(8)));
typedef float v4f __attribute__((ext_vector_type(4)));

// ---------------------------------------------------------------------------
// R16: full revert to the R0 row-major configuration (measured 245.5us),
// with ONE delta: the aggregate inner loop gets R15's proven latency/VALU
// fixes (8-deep up-front srcs issue, unconditional gathers, fma_mix
// accumulate). Ledger: sliced-agg rest=151us (R3: 287.6-136.5, R5:
// 259.5-108 — consistent) => baseline aggregates were ~31.5us each, i.e.
// FASTER than sliced v4's 36us. Slicing cut FETCH 205->21MB but the kernel
// is latency-bound, so traffic never became time; 64B requests + 4x srcs
// re-reads cost ~4.5us/dispatch. Row-major keeps 1KB/instr gathers.
// ---------------------------------------------------------------------------

// ---------------------------------------------------------------------------
// Edge-partitioned LDS histogram (R8-proven) + merged W-prep role (3 tail
// blocks transpose W1/2/3 to fp16 [n][k] for MFMA B-frags).
// ---------------------------------------------------------------------------
__global__ __launch_bounds__(HT) void hist_kernel(const int* __restrict__ src,
                                                  const int* __restrict__ dst,
                                                  unsigned* __restrict__ partial_out,
                                                  unsigned* __restrict__ partial_in,
                                                  unsigned char* __restrict__ lrank,
                                                  const float* __restrict__ W1,
                                                  const float* __restrict__ W2,
                                                  const float* __restrict__ W3,
                                                  _Float16* __restrict__ wt,
                                                  int nE, int W, int epb) {
    const int t = threadIdx.x;
    if ((int)blockIdx.x >= 2 * HB) {                 // W-prep role
        const int l = blockIdx.x - 2 * HB;
        const float* Wsrc = (l == 0) ? W1 : ((l == 1) ? W2 : W3);
        _Float16* o = wt + (size_t)l * D * D;
        for (int i = t; i < D * D; i += HT) {
            const int k = i >> 7, n = i & 127;
            o[n * D + k] = (_Float16)Wsrc[i];
        }
        return;
    }
    __shared__ unsigned lcnt[WMAX];
    const bool is_dst = (blockIdx.x < HB);
    const int b = is_dst ? blockIdx.x : (blockIdx.x - HB);
    for (int i = t; i < W; i += HT) lcnt[i] = 0;
    __syncthreads();
    const int e0 = b * epb;
    const int e1 = min(nE, e0 + epb);
    if (is_dst) {
        for (int e = e0 + t; e < e1; e += HT) {
            const int d = dst[e];
            const unsigned sh = (unsigned)(d & 3) * 8u;
            const unsigned old = atomicAdd(&lcnt[d >> 2], 1u << sh);
            lrank[e] = (unsigned char)((old >> sh) & 0xffu);
        }
    } else {
        for (int e = e0 + t; e < e1; e += HT) {
            const int s = src[e];
            atomicAdd(&lcnt[s >> 2], 1u << ((unsigned)(s & 3) * 8u));
        }
    }
    __syncthreads();
    unsigned* g = (is_dst ? partial_in : partial_out) + (size_t)b * W;
    for (int i = t; i < W; i += HT) g[i] = lcnt[i];
}

// ---------------------------------------------------------------------------
// Reduce 128 partials per node-word (byte-parallel; totals < 256).
// ---------------------------------------------------------------------------
__global__ __launch_bounds__(256) void reduce_hist_kernel(const unsigned* __restrict__ partial_out,
                                                          const unsigned* __restrict__ partial_in,
                                                          unsigned* __restrict__ offs_in,
                                                          int* __restrict__ cnt_out,
                                                          int* __restrict__ cnt_in,
                                                          int W, int n, int nbW) {
    const bool is_dst = ((int)blockIdx.x < nbW);
    const int w = (is_dst ? blockIdx.x : (blockIdx.x - nbW)) * 256 + threadIdx.x;
    if (w >= W) return;
    unsigned run = 0;
    if (is_dst) {
#pragma unroll 16
        for (int b = 0; b < HB; ++b) {
            const unsigned c = partial_in[(size_t)b * W + w];
            offs_in[(size_t)b * W + w] = run;
            run += c;
        }
    } else {
#pragma unroll 16
        for (int b = 0; b < HB; ++b) run += partial_out[(size_t)b * W + w];
    }
    int* cnt = is_dst ? cnt_in : cnt_out;
    const int n0 = w * 4;
    const int4 c4 = make_int4((int)(run & 0xffu), (int)((run >> 8) & 0xffu),
                              (int)((run >> 16) & 0xffu), (int)((run >> 24) & 0xffu));
    if (n0 + 3 < n) {
        *(int4*)&cnt[n0] = c4;
    } else {
        const int* cp = &c4.x;
        for (int i = 0; i < 4 && n0 + i < n; ++i) cnt[n0 + i] = cp[i];
    }
}

// ---------------------------------------------------------------------------
// Exclusive scan stage 1.
// ---------------------------------------------------------------------------
__global__ __launch_bounds__(1024) void scan_block_kernel(const int* __restrict__ deg,
                                                          int* __restrict__ rp,
                                                          int* __restrict__ bsum, int n) {
    __shared__ int wsum[16];
    const int t = threadIdx.x;
    const int lane = t & 63;
    const int wid = t >> 6;
    const int i = blockIdx.x * 1024 + t;
    const int v = (i < n) ? deg[i] : 0;
    int s = v;
#pragma unroll
    for (int off = 1; off < 64; off <<= 1) {
        int u = __shfl_up(s, off, 64);
        if (lane >= off) s += u;
    }
    if (lane == 63) wsum[wid] = s;
    __syncthreads();
    if (wid == 0) {
        int ws = (lane < 16) ? wsum[lane] : 0;
#pragma unroll
        for (int off = 1; off < 16; off <<= 1) {
            int u = __shfl_up(ws, off, 64);
            if (lane >= off) ws += u;
        }
        if (lane < 16) wsum[lane] = ws;
    }
    __syncthreads();
    const int excl = s - v + ((wid > 0) ? wsum[wid - 1] : 0);
    if (i < n) rp[i] = excl;
    if (t == 0) bsum[blockIdx.x] = wsum[15];
}

// ---------------------------------------------------------------------------
// Stage 2 fused with norms; rp[n]=E known a priori.
// ---------------------------------------------------------------------------
__global__ __launch_bounds__(1024) void finalize_kernel(int* __restrict__ rp,
                                                        const int* __restrict__ bsum,
                                                        const int* __restrict__ cnt_out,
                                                        const int* __restrict__ cnt_in,
                                                        float* __restrict__ onorm,
                                                        float* __restrict__ inorm,
                                                        int n, int nb, int nE) {
    __shared__ int prefix_s;
    const int t = threadIdx.x;
    if (t < 64) {
        int v = (t < nb && t < (int)blockIdx.x) ? bsum[t] : 0;
#pragma unroll
        for (int off = 1; off < 64; off <<= 1) v += __shfl_xor(v, off, 64);
        if (t == 0) prefix_s = v;
    }
    __syncthreads();
    const int i = blockIdx.x * 1024 + t;
    if (i < n) {
        rp[i] += prefix_s;
        onorm[i] = rsqrtf(fmaxf((float)cnt_out[i], 1.0f));
        inorm[i] = rsqrtf(fmaxf((float)cnt_in[i], 1.0f));
    }
    if (blockIdx.x == 0 && t == 0) rp[n] = nE;
}

// ---------------------------------------------------------------------------
// FUSED: GEMM1 (y1 = (x@W1)*onorm -> fp16, MFMA) + atomic-free CSR fill.
// R12-proven: independent work, disjoint resources; fill blocks carry NO LDS
// so they keep full wave residency.
// ---------------------------------------------------------------------------
__global__ __launch_bounds__(1024) void gemm1_fill_kernel(
    const float* __restrict__ x, const _Float16* __restrict__ wt,
    const float* __restrict__ onorm, __half* __restrict__ y1, int nrows,
    const int* __restrict__ src, const int* __restrict__ dst,
    const unsigned char* __restrict__ lrank, const unsigned* __restrict__ offs_in,
    const int* __restrict__ rp, int* __restrict__ srcs_sorted,
    int nE, int epb, int W, int nGemmBlocks) {
    __shared__ _Float16 sA[128 * 136];
    __shared__ _Float16 sB[128 * 136];
    const int t = threadIdx.x;

    if ((int)blockIdx.x >= nGemmBlocks) {
        // ---- fill role: one edge per thread ----
        const int e = (blockIdx.x - nGemmBlocks) * 1024 + t;
        if (e < nE) {
            const int d = dst[e];
            const int b = e / epb;
            const unsigned off =
                (offs_in[(size_t)b * W + (d >> 2)] >> ((unsigned)(d & 3) * 8u)) & 0xffu;
            srcs_sorted[rp[d] + (int)off + (int)lrank[e]] = src[e];
        }
        return;
    }

    // ---- GEMM role: 128x128 tile, 16 waves ----
    const int row0 = blockIdx.x * 128;
    const int rr = t >> 4;      // 64 staging rows per pass
    const int c8 = t & 15;
#pragma unroll
    for (int pass = 0; pass < 2; ++pass) {
        const int row = pass * 64 + rr;
        *(float4*)&sB[row * 136 + c8 * 8] = *(const float4*)&wt[(size_t)row * D + c8 * 8];
        const int grow = row0 + row;
        float4 u0 = make_float4(0.f, 0.f, 0.f, 0.f);
        float4 u1 = u0;
        if (grow < nrows) {
            const float* ap = x + (size_t)grow * D + c8 * 8;
            u0 = ((const float4*)ap)[0];
            u1 = ((const float4*)ap)[1];
        }
        v8h hv;
        hv[0] = (_Float16)u0.x; hv[1] = (_Float16)u0.y;
        hv[2] = (_Float16)u0.z; hv[3] = (_Float16)u0.w;
        hv[4] = (_Float16)u1.x; hv[5] = (_Float16)u1.y;
        hv[6] = (_Float16)u1.z; hv[7] = (_Float16)u1.w;
        *(v8h*)&sA[row * 136 + c8 * 8] = hv;
    }
    __syncthreads();

    const int w = t >> 6;       // 16 waves
    const int lane = t & 63;
    const int m16 = lane & 15;
    const int quad = lane >> 4;
    const int rt = w >> 1;      // row-tile 0..7
    const int ch = w & 1;       // col half 0..1

    v4f c[4];
#pragma unroll
    for (int ct = 0; ct < 4; ++ct) c[ct] = (v4f){0.f, 0.f, 0.f, 0.f};

#pragma unroll
    for (int ks = 0; ks < 4; ++ks) {
        const v8h a = *(const v8h*)&sA[(rt * 16 + m16) * 136 + ks * 32 + quad * 8];
#pragma unroll
        for (int ct = 0; ct < 4; ++ct) {
            const v8h b = *(const v8h*)&sB[((ch * 4 + ct) * 16 + m16) * 136 + ks * 32 + quad * 8];
            c[ct] = __builtin_amdgcn_mfma_f32_16x16x32_f16(a, b, c[ct], 0, 0, 0);
        }
    }

#pragma unroll
    for (int r = 0; r < 4; ++r) {
        const int row = row0 + rt * 16 + quad * 4 + r;
        if (row < nrows) {
            const float osc = onorm[row];
#pragma unroll
            for (int ct = 0; ct < 4; ++ct) {
                const int col = (ch * 4 + ct) * 16 + m16;
                y1[(size_t)row * D + col] = __float2half(c[ct][r] * osc);
            }
        }
    }
}

// ---------------------------------------------------------------------------
// Aggregation v5: row-major 256B wide gather (R11-proven shape: wave-per-
// node, 4 rows per gather instruction = 1KB/instr, no LDS, full residency)
// + R15-proven latency/VALU fixes:
//  (a) 8-deep up-front issue: all 8 srcs loads first (exec-masked lanes
//      issue nothing), then 8 UNCONDITIONAL gathers (s[k]=0 -> row 0 is
//      L1-hot, harmless), predicated accumulates last. Both round-trip
//      latencies paid once per wave, 8KB/wave in flight; covers deg<=32
//      (Poisson-16: >99.99% of nodes). Rare tail loop for deg>32.
//  (b) fmaf(float(h),1.0f,acc) -> v_fma_mix_f32, halving accumulate VALU.
// EPI (layer 1): relu(r*inorm+b)*onorm.
// ---------------------------------------------------------------------------
template <bool EPI>
__global__ __launch_bounds__(256) void aggregate_kernel(const __half* __restrict__ xh,
                                                        const float* __restrict__ onorm,
                                                        const float* __restrict__ inorm,
                                                        const float* __restrict__ bias,
                                                        const int* __restrict__ rp,
                                                        const int* __restrict__ srcs,
                                                        __half* __restrict__ agg, int n_nodes) {
    const int node = blockIdx.x * 4 + (threadIdx.x >> 6);
    const int lane = threadIdx.x & 63;
    const int rg = lane >> 4;       // edge slot 0..3
    const int c8 = lane & 15;       // 16B chunk within the 256B row
    if (node >= n_nodes) return;
    const int e0 = rp[node];
    const int e1 = rp[node + 1];
    int e = e0 + rg;

    float acc[8];
#pragma unroll
    for (int j = 0; j < 8; ++j) acc[j] = 0.f;

    // ---- first pass: 8-deep, all loads issued before any use ----
    bool pr[8];
#pragma unroll
    for (int k = 0; k < 8; ++k) pr[k] = (e + 4 * k) < e1;
    int s[8];
#pragma unroll
    for (int k = 0; k < 8; ++k) {
        s[k] = 0;
        if (pr[k]) s[k] = __builtin_nontemporal_load(srcs + e + 4 * k);
    }
    H8 v[8];
#pragma unroll
    for (int k = 0; k < 8; ++k)
        v[k] = ((const H8*)(xh + (size_t)s[k] * D))[c8];
#pragma unroll
    for (int k = 0; k < 8; ++k) {
        if (pr[k]) {
#pragma unroll
            for (int j = 0; j < 4; ++j) {
                acc[2 * j]     = fmaf(__low2float(v[k].h[j]),  1.0f, acc[2 * j]);
                acc[2 * j + 1] = fmaf(__high2float(v[k].h[j]), 1.0f, acc[2 * j + 1]);
            }
        }
    }
    e += 32;

    // ---- rare tail (deg > 32) ----
    while (__any(e < e1)) {
        bool q[4];
        int u[4];
#pragma unroll
        for (int k = 0; k < 4; ++k) {
            q[k] = (e + 4 * k) < e1;
            u[k] = 0;
            if (q[k]) u[k] = __builtin_nontemporal_load(srcs + e + 4 * k);
        }
        H8 w[4];
#pragma unroll
        for (int k = 0; k < 4; ++k)
            w[k] = ((const H8*)(xh + (size_t)u[k] * D))[c8];
#pragma unroll
        for (int k = 0; k < 4; ++k) {
            if (q[k]) {
#pragma unroll
                for (int j = 0; j < 4; ++j) {
                    acc[2 * j]     = fmaf(__low2float(w[k].h[j]),  1.0f, acc[2 * j]);
                    acc[2 * j + 1] = fmaf(__high2float(w[k].h[j]), 1.0f, acc[2 * j + 1]);
                }
            }
        }
        e += 16;
    }

    float r[8];
#pragma unroll
    for (int j = 0; j < 8; ++j) r[j] = acc[j];
#pragma unroll
    for (int off = 16; off < 64; off <<= 1)    // reduce over the 4 edge slots
#pragma unroll
        for (int j = 0; j < 8; ++j) r[j] += __shfl_xor(r[j], off, 64);

    if (rg == 0) {
        if (EPI) {
            const float inm = inorm[node];
            const float onm = onorm[node];
            const float4 bv0 = ((const float4*)bias)[c8 * 2];
            const float4 bv1 = ((const float4*)bias)[c8 * 2 + 1];
            const float* bp0 = &bv0.x;
            const float* bp1 = &bv1.x;
#pragma unroll
            for (int j = 0; j < 4; ++j) {
                r[j]     = fmaxf(fmaf(r[j],     inm, bp0[j]), 0.f) * onm;
                r[j + 4] = fmaxf(fmaf(r[j + 4], inm, bp1[j]), 0.f) * onm;
            }
        }
        H8 h;
#pragma unroll
        for (int j = 0; j < 4; ++j) h.h[j] = __floats2half2_rn(r[2 * j], r[2 * j + 1]);
        ((H8*)(agg + (size_t)node * D))[c8] = h;
    }
}

// ---------------------------------------------------------------------------
// MFMA GEMM for layers 2/3 (R9-proven). 128x128 tile, fp16 operands, fp32
// acc. LDS stride 136 halves. Epilogue: FULL(*inorm+bias), RELU, OSCALE,
// OUT16. A is fp16 row-major.
// ---------------------------------------------------------------------------
template <bool FULL, bool RELU, bool OSCALE, bool OUT16>
__global__ __launch_bounds__(256) void gemm_mfma_kernel(const __half* __restrict__ Ah,
                                                        const _Float16* __restrict__ Wt,
                                                        const float* __restrict__ bias,
                                                        const float* __restrict__ inorm,
                                                        const float* __restrict__ onorm,
                                                        void* __restrict__ outv, int nrows) {
    __shared__ _Float16 sA[128 * 136];
    __shared__ _Float16 sB[128 * 136];
    const int t = threadIdx.x;
    const int row0 = blockIdx.x * 128;
    const int rr = t >> 4;
    const int c8 = t & 15;

#pragma unroll
    for (int pass = 0; pass < 8; ++pass) {
        const int row = pass * 16 + rr;
        *(float4*)&sB[row * 136 + c8 * 8] = *(const float4*)&Wt[(size_t)row * D + c8 * 8];
        const int grow = row0 + row;
        float4 v = make_float4(0.f, 0.f, 0.f, 0.f);
        if (grow < nrows)
            v = *(const float4*)((const _Float16*)Ah + (size_t)grow * D + c8 * 8);
        *(float4*)&sA[row * 136 + c8 * 8] = v;
    }
    __syncthreads();

    const int w = t >> 6;
    const int lane = t & 63;
    const int m16 = lane & 15;
    const int quad = lane >> 4;

    v4f c[2][8];
#pragma unroll
    for (int rt = 0; rt < 2; ++rt)
#pragma unroll
        for (int ct = 0; ct < 8; ++ct) c[rt][ct] = (v4f){0.f, 0.f, 0.f, 0.f};

#pragma unroll
    for (int ks = 0; ks < 4; ++ks) {
        v8h afr[2], bfr[8];
#pragma unroll
        for (int rt = 0; rt < 2; ++rt)
            afr[rt] = *(const v8h*)&sA[(w * 32 + rt * 16 + m16) * 136 + ks * 32 + quad * 8];
#pragma unroll
        for (int ct = 0; ct < 8; ++ct)
            bfr[ct] = *(const v8h*)&sB[(ct * 16 + m16) * 136 + ks * 32 + quad * 8];
#pragma unroll
        for (int rt = 0; rt < 2; ++rt)
#pragma unroll
            for (int ct = 0; ct < 8; ++ct)
                c[rt][ct] = __builtin_amdgcn_mfma_f32_16x16x32_f16(afr[rt], bfr[ct], c[rt][ct], 0, 0, 0);
    }

#pragma unroll
    for (int rt = 0; rt < 2; ++rt) {
#pragma unroll
        for (int r = 0; r < 4; ++r) {
            const int row = row0 + w * 32 + rt * 16 + quad * 4 + r;
            if (row < nrows) {
                const float inm = FULL ? inorm[row] : 1.0f;
                const float osc = OSCALE ? onorm[row] : 1.0f;
#pragma unroll
                for (int ct = 0; ct < 8; ++ct) {
                    const int col = ct * 16 + m16;
                    float v = c[rt][ct][r];
                    if (FULL) v = fmaf(v, inm, bias[col]);
                    if (RELU) v = fmaxf(v, 0.f);
                    if (OSCALE) v *= osc;
                    if (OUT16) ((__half*)outv)[(size_t)row * D + col] = __float2half(v);
                    else       ((float*)outv)[(size_t)row * D + col] = v;
                }
            }
        }
    }
}

// ---------------------------------------------------------------------------
// Host launch
// ---------------------------------------------------------------------------
extern "C" void kernel_launch(void* const* d_in, const int* in_sizes, int n_in,
                              void* d_out, int out_size, void* d_ws, size_t ws_size,
                              hipStream_t stream) {
    const float* x   = (const float*)d_in[0];
    const int*   src = (const int*)d_in[1];
    const int*   dst = (const int*)d_in[2];
    const float* W1  = (const float*)d_in[3];
    const float* b1  = (const float*)d_in[4];
    const float* W2  = (const float*)d_in[5];
    const float* b2  = (const float*)d_in[6];
    const float* W3  = (const float*)d_in[7];
    const float* b3  = (const float*)d_in[8];

    const int N = in_sizes[0] / D;   // 50000
    const int E = in_sizes[1];       // 800000

    char* p = (char*)d_ws;
    auto alloc = [&](size_t bytes) -> void* {
        void* r = (void*)p;
        p += (bytes + 255) & ~(size_t)255;
        return r;
    };
    int*           cnt_out = (int*)alloc((size_t)N * 4);
    int*           cnt_in  = (int*)alloc((size_t)N * 4);
    int*           rp      = (int*)alloc((size_t)(N + 1) * 4);
    int*           bsum    = (int*)alloc(1024 * 4);
    float*         onorm   = (float*)alloc((size_t)N * 4);
    float*         inorm   = (float*)alloc((size_t)N * 4);
    int*           srcs    = (int*)alloc((size_t)E * 4);
    unsigned char* lrank   = (unsigned char*)alloc((size_t)E);
    _Float16*      wt      = (_Float16*)alloc((size_t)3 * D * D * 2);
    __half*        hbuf0   = (__half*)alloc((size_t)N * D * 2);  // y1, then h2
    __half*        hbuf1   = (__half*)alloc((size_t)N * D * 2);  // h1
    char*          scratch = (char*)alloc((size_t)3 * HB * ((N + 3) / 4) * 4);  // 19.2MB

    const int W = (N + 3) / 4;              // 12500 packed histogram words
    const int epb = (E + HB - 1) / HB;      // 6250 edges per histogram block
    unsigned* partial_in  = (unsigned*)scratch;
    unsigned* partial_out = partial_in + (size_t)HB * W;
    unsigned* offs_in     = partial_out + (size_t)HB * W;
    __half*   abuf        = (__half*)scratch;                  // a2, a3 (fp16)
    float*    outf        = (float*)d_out;

    const int nb = (N + 1023) / 1024;       // 49
    const int nbW = (W + 255) / 256;        // 49
    const int gemmGrid = (N + 127) / 128;   // 391
    const int fillGrid = (E + 1023) / 1024; // 782
    const int aggGrid = (N + 3) / 4;        // 12500

    // Graph build (hist + W-prep merged); no global atomics, no memset
    hist_kernel<<<2 * HB + 3, HT, 0, stream>>>(src, dst, partial_out, partial_in, lrank,
                                               W1, W2, W3, wt, E, W, epb);
    reduce_hist_kernel<<<2 * nbW, 256, 0, stream>>>(partial_out, partial_in, offs_in,
                                                    cnt_out, cnt_in, W, N, nbW);
    scan_block_kernel<<<nb, 1024, 0, stream>>>(cnt_in, rp, bsum, N);
    finalize_kernel<<<nb, 1024, 0, stream>>>(rp, bsum, cnt_out, cnt_in, onorm, inorm, N, nb, E);

    // Fused: GEMM1 (y1 = (x@W1)*onorm -> fp16) + CSR fill (independent work)
    gemm1_fill_kernel<<<gemmGrid + fillGrid, 1024, 0, stream>>>(
        x, wt, onorm, hbuf0, N,
        src, dst, lrank, offs_in, rp, srcs, E, epb, W, gemmGrid);

    // Layer 1 aggregate + full epilogue -> h1 fp16
    aggregate_kernel<true><<<aggGrid, 256, 0, stream>>>(
        hbuf0, onorm, inorm, b1, rp, srcs, hbuf1, N);
    // Layer 2: a2 = agg(h1) fp16; h2 = relu((a2@W2)*inorm+b2)*onorm -> fp16
    aggregate_kernel<false><<<aggGrid, 256, 0, stream>>>(
        hbuf1, onorm, inorm, b2, rp, srcs, abuf, N);
    gemm_mfma_kernel<true, true, true, true><<<gemmGrid, 256, 0, stream>>>(
        abuf, wt + (size_t)D * D, b2, inorm, onorm, hbuf0, N);
    // Layer 3: a3 = agg(h2) fp16; out = (a3@W3)*inorm+b3 -> fp32 d_out
    aggregate_kernel<false><<<aggGrid, 256, 0, stream>>>(
        hbuf0, onorm, inorm, b3, rp, srcs, abuf, N);
    gemm_mfma_kernel<true, false, false, false><<<gemmGrid, 256, 0, stream>>>(
        abuf, wt + (size_t)2 * D * D, b3, inorm, onorm, outf, N);
}